// Round 1
// baseline (2861.467 us; speedup 1.0000x reference)
//
#include <hip/hip_runtime.h>
#include <math.h>
#include <float.h>

// Problem constants (from reference setup_inputs)
#define B   256
#define D   256
#define D1  1024
#define D2  512
#define D3  256
#define NDIST (D1 + D2 + D3)   // 1792
#define CHUNK 32               // batches per V2 scratch chunk (16.8 MB)

__device__ __forceinline__ float waveReduceSum(float v) {
    #pragma unroll
    for (int off = 32; off > 0; off >>= 1)
        v += __shfl_down(v, off, 64);
    return v;
}

// ---- W1 row norms ----------------------------------------------------------
__global__ __launch_bounds__(256) void k_rn1(const float* __restrict__ W1,
                                             float* __restrict__ rn1) {
    int gw = (blockIdx.x * blockDim.x + threadIdx.x) >> 6;
    int lane = threadIdx.x & 63;
    if (gw >= D1) return;
    const float* row = W1 + (size_t)gw * D;
    float s = 0.f;
    for (int t = lane; t < D; t += 64) { float v = row[t]; s += v * v; }
    s = waveReduceSum(s);
    if (lane == 0) rn1[gw] = sqrtf(s);
}

// ---- layer 1: z1 = x@W1^T + b1 ; dist1 -------------------------------------
__global__ __launch_bounds__(256) void k_layer1(const float* __restrict__ x,
                                                const float* __restrict__ W1,
                                                const float* __restrict__ b1,
                                                const float* __restrict__ rn1,
                                                float* __restrict__ z1,
                                                float* __restrict__ dists) {
    int gw = (blockIdx.x * blockDim.x + threadIdx.x) >> 6;
    int lane = threadIdx.x & 63;
    int b = gw >> 10;            // / D1
    int j = gw & (D1 - 1);
    if (b >= B) return;
    const float* xr = x + (size_t)b * D;
    const float* wr = W1 + (size_t)j * D;
    float s = 0.f;
    for (int t = lane; t < D; t += 64) s += xr[t] * wr[t];
    s = waveReduceSum(s);
    if (lane == 0) {
        float z = s + b1[j];
        z1[(size_t)b * D1 + j] = z;
        dists[(size_t)b * NDIST + j] = fabsf(z) / rn1[j];
    }
}

// ---- layer 2: z2 = relu(z1)@W2^T + b2 --------------------------------------
__global__ __launch_bounds__(256) void k_layer2(const float* __restrict__ z1,
                                                const float* __restrict__ W2,
                                                const float* __restrict__ b2,
                                                float* __restrict__ z2) {
    int gw = (blockIdx.x * blockDim.x + threadIdx.x) >> 6;
    int lane = threadIdx.x & 63;
    int b = gw >> 9;             // / D2
    int o = gw & (D2 - 1);
    if (b >= B) return;
    const float* h = z1 + (size_t)b * D1;
    const float* wr = W2 + (size_t)o * D1;
    float s = 0.f;
    for (int t = lane; t < D1; t += 64) {
        float hv = h[t];
        hv = hv > 0.f ? hv : 0.f;
        s += hv * wr[t];
    }
    s = waveReduceSum(s);
    if (lane == 0) z2[(size_t)b * D2 + o] = s + b2[o];
}

// ---- layer 3: z3 = relu(z2)@W3^T + b3 --------------------------------------
__global__ __launch_bounds__(256) void k_layer3(const float* __restrict__ z2,
                                                const float* __restrict__ W3,
                                                const float* __restrict__ b3,
                                                float* __restrict__ z3) {
    int gw = (blockIdx.x * blockDim.x + threadIdx.x) >> 6;
    int lane = threadIdx.x & 63;
    int b = gw >> 8;             // / D3
    int p = gw & (D3 - 1);
    if (b >= B) return;
    const float* h = z2 + (size_t)b * D2;
    const float* wr = W3 + (size_t)p * D2;
    float s = 0.f;
    for (int t = lane; t < D2; t += 64) {
        float hv = h[t];
        hv = hv > 0.f ? hv : 0.f;
        s += hv * wr[t];
    }
    s = waveReduceSum(s);
    if (lane == 0) z3[(size_t)b * D3 + p] = s + b3[p];
}

// ---- V2 chunk GEMM: V2c[bc,o,d] = sum_i W2[o,i] * (z1[b,i]>0) * W1[i,d] ----
// 64x64 output tile per block, 256 threads, each thread 4x4 via float4 LDS.
__global__ __launch_bounds__(256) void k_v2(const float* __restrict__ W1,
                                            const float* __restrict__ W2,
                                            const float* __restrict__ z1c,
                                            float* __restrict__ V2c) {
    __shared__ __align__(16) float As[16][68];  // [k][o]
    __shared__ __align__(16) float Bs[16][68];  // [k][d]
    int d0 = blockIdx.x * 64;
    int o0 = blockIdx.y * 64;
    int bc = blockIdx.z;
    int tid = threadIdx.x;
    int tx = tid & 15, ty = tid >> 4;
    const float* zb = z1c + (size_t)bc * D1;
    float acc[4][4] = {};
    for (int kk = 0; kk < D1; kk += 16) {
        #pragma unroll
        for (int r = 0; r < 4; r++) {
            int idx = tid + 256 * r;          // < 1024
            int o = idx >> 4, kq = idx & 15;
            As[kq][o] = W2[(size_t)(o0 + o) * D1 + kk + kq];
        }
        #pragma unroll
        for (int r = 0; r < 4; r++) {
            int idx = tid + 256 * r;          // < 1024
            int i = idx >> 6, d = idx & 63;
            float m = (zb[kk + i] > 0.f) ? 1.f : 0.f;
            Bs[i][d] = m * W1[(size_t)(kk + i) * D + d0 + d];
        }
        __syncthreads();
        #pragma unroll
        for (int kq = 0; kq < 16; kq++) {
            float4 av = *(const float4*)&As[kq][ty * 4];
            float4 bv = *(const float4*)&Bs[kq][tx * 4];
            float a[4] = {av.x, av.y, av.z, av.w};
            float c[4] = {bv.x, bv.y, bv.z, bv.w};
            #pragma unroll
            for (int ai = 0; ai < 4; ai++)
                #pragma unroll
                for (int ci = 0; ci < 4; ci++)
                    acc[ai][ci] += a[ai] * c[ci];
        }
        __syncthreads();
    }
    float* Cb = V2c + ((size_t)bc * D2 + o0) * D + d0;
    #pragma unroll
    for (int ai = 0; ai < 4; ai++) {
        float4 v = make_float4(acc[ai][0], acc[ai][1], acc[ai][2], acc[ai][3]);
        *(float4*)&Cb[(size_t)(ty * 4 + ai) * D + tx * 4] = v;
    }
}

// ---- dist2 from V2 row norms ----------------------------------------------
__global__ __launch_bounds__(256) void k_d2(const float* __restrict__ V2c,
                                            const float* __restrict__ z2,
                                            float* __restrict__ dists, int b0) {
    int gw = (blockIdx.x * blockDim.x + threadIdx.x) >> 6;
    int lane = threadIdx.x & 63;
    int bc = gw >> 9;            // / D2
    int o = gw & (D2 - 1);
    if (bc >= CHUNK) return;
    int b = b0 + bc;
    const float* row = V2c + ((size_t)bc * D2 + o) * D;
    float s = 0.f;
    for (int t = lane; t < D; t += 64) { float v = row[t]; s += v * v; }
    s = waveReduceSum(s);
    if (lane == 0) {
        float z = z2[(size_t)b * D2 + o];
        dists[(size_t)b * NDIST + D1 + o] = fabsf(z) / sqrtf(s);
    }
}

// ---- V3 rows + dist3 (fused, no V3 materialization) ------------------------
// block: 256 threads (thread = d), computes 32 p-rows of V3 for one batch.
__global__ __launch_bounds__(256) void k_v3(const float* __restrict__ V2c,
                                            const float* __restrict__ W3,
                                            const float* __restrict__ z2,
                                            const float* __restrict__ z3,
                                            float* __restrict__ dists, int b0) {
    __shared__ float w3s[16][33];   // [oo][pp]
    __shared__ float red[4][32];
    int pt = blockIdx.x * 32;
    int bc = blockIdx.y;
    int b = b0 + bc;
    int t = threadIdx.x;
    const float* zb2 = z2 + (size_t)b * D2;
    const float* V2b = V2c + (size_t)bc * D2 * D;
    float acc[32] = {};
    for (int o = 0; o < D2; o += 16) {
        __syncthreads();
        #pragma unroll
        for (int r = 0; r < 2; r++) {
            int idx = t + 256 * r;           // < 512
            int pp = idx >> 4, oo = idx & 15;
            w3s[oo][pp] = W3[(size_t)(pt + pp) * D2 + o + oo];
        }
        __syncthreads();
        #pragma unroll
        for (int oo = 0; oo < 16; oo++) {
            float zv = zb2[o + oo];
            float v = (zv > 0.f) ? V2b[(size_t)(o + oo) * D + t] : 0.f;
            #pragma unroll
            for (int pp = 0; pp < 32; pp++) acc[pp] += w3s[oo][pp] * v;
        }
    }
    int lane = t & 63, w = t >> 6;
    #pragma unroll
    for (int pp = 0; pp < 32; pp++) {
        float v = acc[pp] * acc[pp];
        v = waveReduceSum(v);
        if (lane == 0) red[w][pp] = v;
    }
    __syncthreads();
    if (t < 32) {
        float n = red[0][t] + red[1][t] + red[2][t] + red[3][t];
        int p = pt + t;
        float z = z3[(size_t)b * D3 + p];
        dists[(size_t)b * NDIST + D1 + D2 + p] = fabsf(z) / sqrtf(n);
    }
}

// ---- per-batch k smallest sum ---------------------------------------------
__global__ __launch_bounds__(256) void k_topk(const float* __restrict__ dists,
                                              const int* __restrict__ kp,
                                              float* __restrict__ partial) {
    __shared__ float ld[NDIST];
    __shared__ float rv[256];
    __shared__ int   ri[256];
    int b = blockIdx.x;
    int t = threadIdx.x;
    for (int i = t; i < NDIST; i += 256) ld[i] = dists[(size_t)b * NDIST + i];
    __syncthreads();
    int k = *kp;
    if (k > NDIST) k = NDIST;
    float sum = 0.f;
    for (int it = 0; it < k; it++) {
        float mv = FLT_MAX; int mi = -1;
        for (int i = t; i < NDIST; i += 256) {
            float v = ld[i];
            if (v < mv) { mv = v; mi = i; }
        }
        rv[t] = mv; ri[t] = mi;
        __syncthreads();
        for (int s = 128; s > 0; s >>= 1) {
            if (t < s) {
                if (rv[t + s] < rv[t]) { rv[t] = rv[t + s]; ri[t] = ri[t + s]; }
            }
            __syncthreads();
        }
        if (t == 0) { sum += rv[0]; ld[ri[0]] = FLT_MAX; }
        __syncthreads();
    }
    if (t == 0) partial[b] = sum;
}

// ---- final reduce ----------------------------------------------------------
__global__ __launch_bounds__(256) void k_final(const float* __restrict__ partial,
                                               float* __restrict__ out) {
    __shared__ float s[4];
    int t = threadIdx.x;
    float v = (t < B) ? partial[t] : 0.f;
    v = waveReduceSum(v);
    if ((t & 63) == 0) s[t >> 6] = v;
    __syncthreads();
    if (t == 0) out[0] = s[0] + s[1] + s[2] + s[3];
}

extern "C" void kernel_launch(void* const* d_in, const int* in_sizes, int n_in,
                              void* d_out, int out_size, void* d_ws, size_t ws_size,
                              hipStream_t stream) {
    const float* x  = (const float*)d_in[0];
    const float* W1 = (const float*)d_in[1];
    const float* b1 = (const float*)d_in[2];
    const float* W2 = (const float*)d_in[3];
    const float* b2 = (const float*)d_in[4];
    const float* W3 = (const float*)d_in[5];
    const float* b3 = (const float*)d_in[6];
    const int*   kp = (const int*)d_in[7];
    float* outp = (float*)d_out;

    float* ws = (float*)d_ws;
    float* rn1     = ws;                         // 1024
    float* z1      = rn1 + D1;                   // B*D1
    float* z2      = z1 + (size_t)B * D1;        // B*D2
    float* z3      = z2 + (size_t)B * D2;        // B*D3
    float* dists   = z3 + (size_t)B * D3;        // B*NDIST
    float* partial = dists + (size_t)B * NDIST;  // 256
    float* V2c     = partial + 256;              // CHUNK*D2*D (16.8 MB)

    k_rn1<<<D1 / 4, 256, 0, stream>>>(W1, rn1);
    k_layer1<<<(B * D1) / 4, 256, 0, stream>>>(x, W1, b1, rn1, z1, dists);
    k_layer2<<<(B * D2) / 4, 256, 0, stream>>>(z1, W2, b2, z2);
    k_layer3<<<(B * D3) / 4, 256, 0, stream>>>(z2, W3, b3, z3);

    for (int b0 = 0; b0 < B; b0 += CHUNK) {
        k_v2<<<dim3(D / 64, D2 / 64, CHUNK), 256, 0, stream>>>(
            W1, W2, z1 + (size_t)b0 * D1, V2c);
        k_d2<<<(CHUNK * D2) / 4, 256, 0, stream>>>(V2c, z2, dists, b0);
        k_v3<<<dim3(D3 / 32, CHUNK), 256, 0, stream>>>(V2c, W3, z2, z3, dists, b0);
    }

    k_topk<<<B, 256, 0, stream>>>(dists, kp, partial);
    k_final<<<1, 256, 0, stream>>>(partial, outp);
}

// Round 2
// 409.134 us; speedup vs baseline: 6.9940x; 6.9940x over previous
//
#include <hip/hip_runtime.h>
#include <math.h>
#include <float.h>

#define B   256
#define D   256
#define D1  1024
#define D2  512
#define D3  256
#define NDIST (D1 + D2 + D3)   // 1792

typedef __attribute__((ext_vector_type(8))) short short8;
typedef __attribute__((ext_vector_type(4))) float f32x4;

__device__ __forceinline__ float waveReduceSum(float v) {
    #pragma unroll
    for (int off = 32; off > 0; off >>= 1)
        v += __shfl_down(v, off, 64);
    return v;
}

__device__ __forceinline__ unsigned short f2bf(float f) {
    unsigned int u = __float_as_uint(f);
    u = (u + 0x7FFFu + ((u >> 16) & 1u)) >> 16;   // RNE
    return (unsigned short)u;
}

__device__ __forceinline__ void gld16(const void* g, void* l) {
    __builtin_amdgcn_global_load_lds(
        (const __attribute__((address_space(1))) unsigned int*)g,
        (__attribute__((address_space(3))) unsigned int*)l, 16, 0, 0);
}

// ---- zero helper -----------------------------------------------------------
__global__ __launch_bounds__(256) void k_zero(float* __restrict__ p, int n) {
    int i = blockIdx.x * 256 + threadIdx.x;
    if (i < n) p[i] = 0.f;
}

// ---- fp32 -> bf16 copy -----------------------------------------------------
__global__ __launch_bounds__(256) void k_cvt(const float* __restrict__ in,
                                             unsigned short* __restrict__ out, int n) {
    int i = (blockIdx.x * 256 + threadIdx.x) * 4;
    if (i >= n) return;
    float4 v = *(const float4*)(in + i);
    ushort4 o4;
    o4.x = f2bf(v.x); o4.y = f2bf(v.y); o4.z = f2bf(v.z); o4.w = f2bf(v.w);
    *(ushort4*)(out + i) = o4;
}

// ---- W1 [1024][256] fp32  ->  W1T [256][1024] bf16 -------------------------
__global__ __launch_bounds__(256) void k_w1t(const float* __restrict__ W1,
                                             unsigned short* __restrict__ W1T) {
    __shared__ float tile[32][33];
    int i0 = blockIdx.x * 32;   // over D1
    int d0 = blockIdx.y * 32;   // over D
    int tx = threadIdx.x & 31, ty = threadIdx.x >> 5;  // ty 0..7
    #pragma unroll
    for (int r = 0; r < 32; r += 8)
        tile[ty + r][tx] = W1[(size_t)(i0 + ty + r) * D + d0 + tx];
    __syncthreads();
    #pragma unroll
    for (int r = 0; r < 32; r += 8)
        W1T[(size_t)(d0 + ty + r) * D1 + i0 + tx] = f2bf(tile[tx][ty + r]);
}

// ---- mask m1 as AND-able bf16 mask (0x0000 / 0xFFFF) ------------------------
__global__ __launch_bounds__(256) void k_mask1(const float* __restrict__ z1,
                                               unsigned short* __restrict__ m1and, int n) {
    int i = blockIdx.x * 256 + threadIdx.x;
    if (i < n) m1and[i] = (z1[i] > 0.f) ? 0xFFFFu : 0u;
}

// ---- W1 row norms ----------------------------------------------------------
__global__ __launch_bounds__(256) void k_rn1(const float* __restrict__ W1,
                                             float* __restrict__ rn1) {
    int gw = (blockIdx.x * blockDim.x + threadIdx.x) >> 6;
    int lane = threadIdx.x & 63;
    if (gw >= D1) return;
    const float* row = W1 + (size_t)gw * D;
    float s = 0.f;
    for (int t = lane; t < D; t += 64) { float v = row[t]; s += v * v; }
    s = waveReduceSum(s);
    if (lane == 0) rn1[gw] = sqrtf(s);
}

// ---- layer 1: z1 = x@W1^T + b1 ; dist1 -------------------------------------
__global__ __launch_bounds__(256) void k_layer1(const float* __restrict__ x,
                                                const float* __restrict__ W1,
                                                const float* __restrict__ b1,
                                                const float* __restrict__ rn1,
                                                float* __restrict__ z1,
                                                float* __restrict__ dists) {
    int gw = (blockIdx.x * blockDim.x + threadIdx.x) >> 6;
    int lane = threadIdx.x & 63;
    int b = gw >> 10;
    int j = gw & (D1 - 1);
    if (b >= B) return;
    const float* xr = x + (size_t)b * D;
    const float* wr = W1 + (size_t)j * D;
    float s = 0.f;
    for (int t = lane; t < D; t += 64) s += xr[t] * wr[t];
    s = waveReduceSum(s);
    if (lane == 0) {
        float z = s + b1[j];
        z1[(size_t)b * D1 + j] = z;
        dists[(size_t)b * NDIST + j] = fabsf(z) / rn1[j];
    }
}

// ---- layer 2: z2 = relu(z1)@W2^T + b2 --------------------------------------
__global__ __launch_bounds__(256) void k_layer2(const float* __restrict__ z1,
                                                const float* __restrict__ W2,
                                                const float* __restrict__ b2,
                                                float* __restrict__ z2) {
    int gw = (blockIdx.x * blockDim.x + threadIdx.x) >> 6;
    int lane = threadIdx.x & 63;
    int b = gw >> 9;
    int o = gw & (D2 - 1);
    if (b >= B) return;
    const float* h = z1 + (size_t)b * D1;
    const float* wr = W2 + (size_t)o * D1;
    float s = 0.f;
    for (int t = lane; t < D1; t += 64) {
        float hv = h[t];
        hv = hv > 0.f ? hv : 0.f;
        s += hv * wr[t];
    }
    s = waveReduceSum(s);
    if (lane == 0) z2[(size_t)b * D2 + o] = s + b2[o];
}

// ---- layer 3: z3 = relu(z2)@W3^T + b3 --------------------------------------
__global__ __launch_bounds__(256) void k_layer3(const float* __restrict__ z2,
                                                const float* __restrict__ W3,
                                                const float* __restrict__ b3,
                                                float* __restrict__ z3) {
    int gw = (blockIdx.x * blockDim.x + threadIdx.x) >> 6;
    int lane = threadIdx.x & 63;
    int b = gw >> 8;
    int p = gw & (D3 - 1);
    if (b >= B) return;
    const float* h = z2 + (size_t)b * D2;
    const float* wr = W3 + (size_t)p * D2;
    float s = 0.f;
    for (int t = lane; t < D2; t += 64) {
        float hv = h[t];
        hv = hv > 0.f ? hv : 0.f;
        s += hv * wr[t];
    }
    s = waveReduceSum(s);
    if (lane == 0) z3[(size_t)b * D3 + p] = s + b3[p];
}

// ---- GEMM1 (MFMA bf16): C[d][o] = sum_i (m1*W1T)[d][i] * W2[o][i] ----------
// V2T = (m1 (.) W1)^T W2^T ; per batch.  M=256(d), N=512(o), K=1024(i).
// Tile 128x128, BK=32, 4 waves each 64x64 (4x4 of 16x16x32 MFMA).
// Epilogue: atomic row norms ||V2[:,o]||^2 over d, + m2-masked bf16 write of V2T.
__global__ __launch_bounds__(256) void k_gemm1(
    const unsigned short* __restrict__ W1T,    // [256][1024] bf16
    const unsigned short* __restrict__ W2b,    // [512][1024] bf16
    const unsigned short* __restrict__ m1and,  // [B][1024]
    const float* __restrict__ z2,              // [B][512]
    unsigned short* __restrict__ V2mT,         // [CH][256][512] bf16
    float* __restrict__ norm2,                 // [B][512]
    int b0)
{
    __shared__ unsigned short As[128 * 32];
    __shared__ unsigned short Bs[128 * 32];
    int m0 = blockIdx.x * 128;     // d
    int o0 = blockIdx.y * 128;     // o
    int bc = blockIdx.z;
    int b  = b0 + bc;
    int tid = threadIdx.x;
    int lane = tid & 63, wid = tid >> 6;
    int quad = lane >> 4, l16 = lane & 15;
    int wm = (wid >> 1) * 64, wn = (wid & 1) * 64;
    int row = tid >> 2;            // 0..63
    int cg  = tid & 3;             // 16B group within 32-wide k tile
    const unsigned short* mrow = m1and + (size_t)b * D1;

    f32x4 acc[4][4];
    #pragma unroll
    for (int i = 0; i < 4; i++)
        #pragma unroll
        for (int j = 0; j < 4; j++) acc[i][j] = (f32x4)0.f;

    for (int kk = 0; kk < D1; kk += 32) {
        uint4 mv = *(const uint4*)(mrow + kk + cg * 8);
        #pragma unroll
        for (int r = 0; r < 2; r++) {
            int rr = row + 64 * r;
            uint4 wv = *(const uint4*)(W1T + (size_t)(m0 + rr) * D1 + kk + cg * 8);
            wv.x &= mv.x; wv.y &= mv.y; wv.z &= mv.z; wv.w &= mv.w;
            *(uint4*)(&As[rr * 32 + cg * 8]) = wv;
        }
        #pragma unroll
        for (int r = 0; r < 2; r++) {
            gld16(W2b + (size_t)(o0 + row + 64 * r) * D1 + kk + cg * 8,
                  (void*)(Bs + (size_t)wid * 512 + (size_t)r * 2048));
        }
        __syncthreads();
        short8 a[4], bf[4];
        #pragma unroll
        for (int mt = 0; mt < 4; mt++)
            a[mt] = *(const short8*)(&As[(wm + mt * 16 + l16) * 32 + quad * 8]);
        #pragma unroll
        for (int nt = 0; nt < 4; nt++)
            bf[nt] = *(const short8*)(&Bs[(wn + nt * 16 + l16) * 32 + quad * 8]);
        #pragma unroll
        for (int mt = 0; mt < 4; mt++)
            #pragma unroll
            for (int nt = 0; nt < 4; nt++)
                acc[mt][nt] = __builtin_amdgcn_mfma_f32_16x16x32_bf16(
                    a[mt], bf[nt], acc[mt][nt], 0, 0, 0);
        __syncthreads();
    }

    // z2 (mask m2) per nt for this lane's column o
    float z2v[4];
    #pragma unroll
    for (int nt = 0; nt < 4; nt++)
        z2v[nt] = z2[(size_t)b * D2 + o0 + wn + nt * 16 + l16];

    // norms: sum over d (rows) for each column o
    #pragma unroll
    for (int nt = 0; nt < 4; nt++) {
        float s = 0.f;
        #pragma unroll
        for (int mt = 0; mt < 4; mt++)
            #pragma unroll
            for (int r = 0; r < 4; r++) { float v = acc[mt][nt][r]; s += v * v; }
        s += __shfl_down(s, 32, 64);
        s += __shfl_down(s, 16, 64);
        if (lane < 16)
            atomicAdd(&norm2[(size_t)b * D2 + o0 + wn + nt * 16 + lane], s);
    }

    // m2-masked bf16 transposed write: V2mT[bc][d][o]
    unsigned short* outb = V2mT + (size_t)bc * (D * D2);
    #pragma unroll
    for (int mt = 0; mt < 4; mt++) {
        int dbase = m0 + wm + mt * 16 + quad * 4;
        #pragma unroll
        for (int r = 0; r < 4; r++) {
            #pragma unroll
            for (int nt = 0; nt < 4; nt++) {
                int o = o0 + wn + nt * 16 + l16;
                float v = (z2v[nt] > 0.f) ? acc[mt][nt][r] : 0.f;
                outb[(size_t)(dbase + r) * D2 + o] = f2bf(v);
            }
        }
    }
}

// ---- GEMM2 (MFMA bf16): V3[p][d] = sum_o W3[p][o] * V2mT[d][o] -------------
// M=256(p), N=256(d), K=512(o). Norms only (sum over d columns), atomic.
__global__ __launch_bounds__(256) void k_gemm2(
    const unsigned short* __restrict__ W3b,    // [256][512] bf16
    const unsigned short* __restrict__ V2mT,   // [CH][256][512] bf16
    float* __restrict__ norm3,                 // [B][256]
    int b0)
{
    __shared__ unsigned short As[128 * 32];
    __shared__ unsigned short Bs[128 * 32];
    int p0 = blockIdx.x * 128;
    int n0 = blockIdx.y * 128;
    int bc = blockIdx.z;
    int b  = b0 + bc;
    int tid = threadIdx.x;
    int lane = tid & 63, wid = tid >> 6;
    int quad = lane >> 4, l16 = lane & 15;
    int wm = (wid >> 1) * 64, wn = (wid & 1) * 64;
    int row = tid >> 2, cg = tid & 3;
    const unsigned short* Bsrc = V2mT + (size_t)bc * (D * D2);

    f32x4 acc[4][4];
    #pragma unroll
    for (int i = 0; i < 4; i++)
        #pragma unroll
        for (int j = 0; j < 4; j++) acc[i][j] = (f32x4)0.f;

    for (int kk = 0; kk < D2; kk += 32) {
        #pragma unroll
        for (int r = 0; r < 2; r++) {
            gld16(W3b + (size_t)(p0 + row + 64 * r) * D2 + kk + cg * 8,
                  (void*)(As + (size_t)wid * 512 + (size_t)r * 2048));
            gld16(Bsrc + (size_t)(n0 + row + 64 * r) * D2 + kk + cg * 8,
                  (void*)(Bs + (size_t)wid * 512 + (size_t)r * 2048));
        }
        __syncthreads();
        short8 a[4], bf[4];
        #pragma unroll
        for (int mt = 0; mt < 4; mt++)
            a[mt] = *(const short8*)(&As[(wm + mt * 16 + l16) * 32 + quad * 8]);
        #pragma unroll
        for (int nt = 0; nt < 4; nt++)
            bf[nt] = *(const short8*)(&Bs[(wn + nt * 16 + l16) * 32 + quad * 8]);
        #pragma unroll
        for (int mt = 0; mt < 4; mt++)
            #pragma unroll
            for (int nt = 0; nt < 4; nt++)
                acc[mt][nt] = __builtin_amdgcn_mfma_f32_16x16x32_bf16(
                    a[mt], bf[nt], acc[mt][nt], 0, 0, 0);
        __syncthreads();
    }

    // norm over d (columns): reduce across l16 within quad, then atomic per p-row
    #pragma unroll
    for (int mt = 0; mt < 4; mt++)
        #pragma unroll
        for (int r = 0; r < 4; r++) {
            float s = 0.f;
            #pragma unroll
            for (int nt = 0; nt < 4; nt++) { float v = acc[mt][nt][r]; s += v * v; }
            s += __shfl_down(s, 8, 64);
            s += __shfl_down(s, 4, 64);
            s += __shfl_down(s, 2, 64);
            s += __shfl_down(s, 1, 64);
            if (l16 == 0)
                atomicAdd(&norm3[(size_t)b * D3 + p0 + wm + mt * 16 + quad * 4 + r], s);
        }
}

// ---- dists from norms ------------------------------------------------------
__global__ __launch_bounds__(256) void k_dist2(const float* __restrict__ z2,
                                               const float* __restrict__ norm2,
                                               float* __restrict__ dists) {
    int idx = blockIdx.x * 256 + threadIdx.x;     // B*D2
    int b = idx >> 9, o = idx & (D2 - 1);
    dists[(size_t)b * NDIST + D1 + o] = fabsf(z2[idx]) / sqrtf(norm2[idx]);
}

__global__ __launch_bounds__(256) void k_dist3(const float* __restrict__ z3,
                                               const float* __restrict__ norm3,
                                               float* __restrict__ dists) {
    int idx = blockIdx.x * 256 + threadIdx.x;     // B*D3
    int b = idx >> 8, p = idx & (D3 - 1);
    dists[(size_t)b * NDIST + D1 + D2 + p] = fabsf(z3[idx]) / sqrtf(norm3[idx]);
}

// ---- per-batch k smallest sum ---------------------------------------------
__global__ __launch_bounds__(256) void k_topk(const float* __restrict__ dists,
                                              const int* __restrict__ kp,
                                              float* __restrict__ partial) {
    __shared__ float ld[NDIST];
    __shared__ float rv[256];
    __shared__ int   ri[256];
    int b = blockIdx.x;
    int t = threadIdx.x;
    for (int i = t; i < NDIST; i += 256) ld[i] = dists[(size_t)b * NDIST + i];
    __syncthreads();
    int k = *kp;
    if (k > NDIST) k = NDIST;
    float sum = 0.f;
    for (int it = 0; it < k; it++) {
        float mv = FLT_MAX; int mi = -1;
        for (int i = t; i < NDIST; i += 256) {
            float v = ld[i];
            if (v < mv) { mv = v; mi = i; }
        }
        rv[t] = mv; ri[t] = mi;
        __syncthreads();
        for (int s = 128; s > 0; s >>= 1) {
            if (t < s) {
                if (rv[t + s] < rv[t]) { rv[t] = rv[t + s]; ri[t] = ri[t + s]; }
            }
            __syncthreads();
        }
        if (t == 0) { sum += rv[0]; ld[ri[0]] = FLT_MAX; }
        __syncthreads();
    }
    if (t == 0) partial[b] = sum;
}

// ---- final reduce ----------------------------------------------------------
__global__ __launch_bounds__(256) void k_final(const float* __restrict__ partial,
                                               float* __restrict__ out) {
    __shared__ float s[4];
    int t = threadIdx.x;
    float v = (t < B) ? partial[t] : 0.f;
    v = waveReduceSum(v);
    if ((t & 63) == 0) s[t >> 6] = v;
    __syncthreads();
    if (t == 0) out[0] = s[0] + s[1] + s[2] + s[3];
}

extern "C" void kernel_launch(void* const* d_in, const int* in_sizes, int n_in,
                              void* d_out, int out_size, void* d_ws, size_t ws_size,
                              hipStream_t stream) {
    const float* x  = (const float*)d_in[0];
    const float* W1 = (const float*)d_in[1];
    const float* b1 = (const float*)d_in[2];
    const float* W2 = (const float*)d_in[3];
    const float* b2 = (const float*)d_in[4];
    const float* W3 = (const float*)d_in[5];
    const float* b3 = (const float*)d_in[6];
    const int*   kp = (const int*)d_in[7];
    float* outp = (float*)d_out;

    // ---- workspace layout ----
    float* ws = (float*)d_ws;
    float* rn1     = ws;                          // 1024
    float* z1      = rn1 + D1;                    // B*D1
    float* z2      = z1 + (size_t)B * D1;         // B*D2
    float* z3      = z2 + (size_t)B * D2;         // B*D3
    float* dists   = z3 + (size_t)B * D3;         // B*NDIST
    float* partial = dists + (size_t)B * NDIST;   // 256
    float* norm2   = partial + 256;               // B*D2
    float* norm3   = norm2 + (size_t)B * D2;      // B*D3
    unsigned short* us_base = (unsigned short*)(norm3 + (size_t)B * D3);
    unsigned short* W1T   = us_base;                        // 256*1024
    unsigned short* W2b   = W1T + (size_t)D * D1;           // 512*1024
    unsigned short* W3b   = W2b + (size_t)D2 * D1;          // 256*512
    unsigned short* m1and = W3b + (size_t)D3 * D2;          // B*1024
    unsigned short* V2mT  = m1and + (size_t)B * D1;         // CH*256*512

    size_t base_bytes = (size_t)((char*)V2mT - (char*)d_ws);
    int CH = 8;
    const int cands[6] = {256, 128, 64, 32, 16, 8};
    for (int c = 0; c < 6; c++) {
        size_t need = base_bytes + (size_t)cands[c] * D * D2 * sizeof(unsigned short);
        if (need <= ws_size) { CH = cands[c]; break; }
    }

    // zero norms (norm2,norm3 contiguous)
    k_zero<<<(B * D2 + B * D3 + 255) / 256, 256, 0, stream>>>(norm2, B * D2 + B * D3);

    // bf16 conversions
    k_cvt<<<(D2 * D1 / 4 + 255) / 256, 256, 0, stream>>>(W2, W2b, D2 * D1);
    k_cvt<<<(D3 * D2 / 4 + 255) / 256, 256, 0, stream>>>(W3, W3b, D3 * D2);
    k_w1t<<<dim3(D1 / 32, D / 32), 256, 0, stream>>>(W1, W1T);

    // exact fp32 layer pass
    k_rn1<<<D1 / 4, 256, 0, stream>>>(W1, rn1);
    k_layer1<<<(B * D1) / 4, 256, 0, stream>>>(x, W1, b1, rn1, z1, dists);
    k_layer2<<<(B * D2) / 4, 256, 0, stream>>>(z1, W2, b2, z2);
    k_layer3<<<(B * D3) / 4, 256, 0, stream>>>(z2, W3, b3, z3);
    k_mask1<<<(B * D1) / 256, 256, 0, stream>>>(z1, m1and, B * D1);

    // batched MFMA GEMMs
    for (int b0 = 0; b0 < B; b0 += CH) {
        k_gemm1<<<dim3(D / 128, D2 / 128, CH), 256, 0, stream>>>(
            W1T, W2b, m1and, z2, V2mT, norm2, b0);
        k_gemm2<<<dim3(D3 / 128, D / 128, CH), 256, 0, stream>>>(
            W3b, V2mT, norm3, b0);
    }

    k_dist2<<<(B * D2) / 256, 256, 0, stream>>>(z2, norm2, dists);
    k_dist3<<<(B * D3) / 256, 256, 0, stream>>>(z3, norm3, dists);

    k_topk<<<B, 256, 0, stream>>>(dists, kp, partial);
    k_final<<<1, 256, 0, stream>>>(partial, outp);
}

// Round 3
// 301.070 us; speedup vs baseline: 9.5043x; 1.3589x over previous
//
#include <hip/hip_runtime.h>
#include <math.h>
#include <float.h>

#define B   256
#define D   256
#define D1  1024
#define D2  512
#define D3  256
#define NDIST (D1 + D2 + D3)   // 1792

typedef __attribute__((ext_vector_type(8))) short short8;
typedef __attribute__((ext_vector_type(4))) float f32x4;

__device__ __forceinline__ float waveReduceSum(float v) {
    #pragma unroll
    for (int off = 32; off > 0; off >>= 1)
        v += __shfl_down(v, off, 64);
    return v;
}

__device__ __forceinline__ unsigned short f2bf(float f) {
    unsigned int u = __float_as_uint(f);
    u = (u + 0x7FFFu + ((u >> 16) & 1u)) >> 16;   // RNE
    return (unsigned short)u;
}
__device__ __forceinline__ float bf2f(unsigned short h) {
    return __uint_as_float(((unsigned int)h) << 16);
}
__device__ __forceinline__ short8 as_s8(uint4 v) {
    union { uint4 u; short8 s; } c; c.u = v; return c.s;
}
__device__ __forceinline__ void gld16(const void* g, void* l) {
    __builtin_amdgcn_global_load_lds(
        (const __attribute__((address_space(1))) unsigned int*)g,
        (__attribute__((address_space(3))) unsigned int*)l, 16, 0, 0);
}

// ---- zero helper -----------------------------------------------------------
__global__ __launch_bounds__(256) void k_zero(float* __restrict__ p, int n) {
    int i = blockIdx.x * 256 + threadIdx.x;
    if (i < n) p[i] = 0.f;
}

// ---- hi/lo split of x, W1, W2, W3 in one dispatch --------------------------
__global__ __launch_bounds__(256) void k_cvtall(
    const float* __restrict__ x,  const float* __restrict__ W1,
    const float* __restrict__ W2, const float* __restrict__ W3,
    unsigned short* __restrict__ xhi,  unsigned short* __restrict__ xlo,
    unsigned short* __restrict__ W1hi, unsigned short* __restrict__ W1lo,
    unsigned short* __restrict__ W2hi, unsigned short* __restrict__ W2lo,
    unsigned short* __restrict__ W3hi, unsigned short* __restrict__ W3lo) {
    int i4 = (blockIdx.x * 256 + threadIdx.x) * 4;
    const float* src; unsigned short *hi, *lo; int off;
    if (i4 < 65536)       { src = x;  hi = xhi;  lo = xlo;  off = i4; }
    else if (i4 < 327680) { src = W1; hi = W1hi; lo = W1lo; off = i4 - 65536; }
    else if (i4 < 851968) { src = W2; hi = W2hi; lo = W2lo; off = i4 - 327680; }
    else                  { src = W3; hi = W3hi; lo = W3lo; off = i4 - 851968; }
    float4 v = *(const float4*)(src + off);
    ushort4 h, l;
    h.x = f2bf(v.x); l.x = f2bf(v.x - bf2f(h.x));
    h.y = f2bf(v.y); l.y = f2bf(v.y - bf2f(h.y));
    h.z = f2bf(v.z); l.z = f2bf(v.z - bf2f(h.z));
    h.w = f2bf(v.w); l.w = f2bf(v.w - bf2f(h.w));
    *(ushort4*)(hi + off) = h;
    *(ushort4*)(lo + off) = l;
}

// ---- W1 [1024][256] fp32 -> W1T [256][1024] bf16 ---------------------------
__global__ __launch_bounds__(256) void k_w1t(const float* __restrict__ W1,
                                             unsigned short* __restrict__ W1T) {
    __shared__ float tile[32][33];
    int i0 = blockIdx.x * 32;   // over D1
    int d0 = blockIdx.y * 32;   // over D
    int tx = threadIdx.x & 31, ty = threadIdx.x >> 5;
    #pragma unroll
    for (int r = 0; r < 32; r += 8)
        tile[ty + r][tx] = W1[(size_t)(i0 + ty + r) * D + d0 + tx];
    __syncthreads();
    #pragma unroll
    for (int r = 0; r < 32; r += 8)
        W1T[(size_t)(d0 + ty + r) * D1 + i0 + tx] = f2bf(tile[tx][ty + r]);
}

// ---- W1 row norms ----------------------------------------------------------
__global__ __launch_bounds__(256) void k_rn1(const float* __restrict__ W1,
                                             float* __restrict__ rn1) {
    int gw = (blockIdx.x * blockDim.x + threadIdx.x) >> 6;
    int lane = threadIdx.x & 63;
    if (gw >= D1) return;
    const float* row = W1 + (size_t)gw * D;
    float s = 0.f;
    for (int t = lane; t < D; t += 64) { float v = row[t]; s += v * v; }
    s = waveReduceSum(s);
    if (lane == 0) rn1[gw] = sqrtf(s);
}

// ---- compensated bf16 MFMA mainloop for a 64x64 tile, C = A @ B^T ----------
// A,B given as hi/lo bf16 row-major [.][KD]. sm = 8192 ushorts of LDS.
template <int KD>
__device__ __forceinline__ void mfma3_64(
    const unsigned short* __restrict__ Ahi, const unsigned short* __restrict__ Alo,
    const unsigned short* __restrict__ Bhi, const unsigned short* __restrict__ Blo,
    int m0, int n0, unsigned short* sm, f32x4 acc[2][2]) {
    int tid = threadIdx.x;
    int l = tid & 63, w = tid >> 6;
    int rsub = l >> 2, cq = l & 3;
    int quad = l >> 4, l16 = l & 15;
    int wm = (w >> 1) * 32, wn = (w & 1) * 32;
    unsigned short* sAh = sm;
    unsigned short* sAl = sm + 2048;
    unsigned short* sBh = sm + 4096;
    unsigned short* sBl = sm + 6144;
    ptrdiff_t dA = Alo - Ahi, dB = Blo - Bhi;
    for (int kk = 0; kk < KD; kk += 32) {
        const unsigned short* pa = Ahi + (size_t)(m0 + w * 16 + rsub) * KD + kk + cq * 8;
        const unsigned short* pb = Bhi + (size_t)(n0 + w * 16 + rsub) * KD + kk + cq * 8;
        gld16(pa,      sAh + w * 512);
        gld16(pa + dA, sAl + w * 512);
        gld16(pb,      sBh + w * 512);
        gld16(pb + dB, sBl + w * 512);
        __syncthreads();
        short8 ah[2], al[2], bh[2], bl[2];
        #pragma unroll
        for (int mt = 0; mt < 2; mt++) {
            int o = (wm + mt * 16 + l16) * 32 + quad * 8;
            ah[mt] = *(const short8*)(sAh + o);
            al[mt] = *(const short8*)(sAl + o);
        }
        #pragma unroll
        for (int nt = 0; nt < 2; nt++) {
            int o = (wn + nt * 16 + l16) * 32 + quad * 8;
            bh[nt] = *(const short8*)(sBh + o);
            bl[nt] = *(const short8*)(sBl + o);
        }
        #pragma unroll
        for (int mt = 0; mt < 2; mt++)
            #pragma unroll
            for (int nt = 0; nt < 2; nt++) {
                acc[mt][nt] = __builtin_amdgcn_mfma_f32_16x16x32_bf16(ah[mt], bh[nt], acc[mt][nt], 0, 0, 0);
                acc[mt][nt] = __builtin_amdgcn_mfma_f32_16x16x32_bf16(ah[mt], bl[nt], acc[mt][nt], 0, 0, 0);
                acc[mt][nt] = __builtin_amdgcn_mfma_f32_16x16x32_bf16(al[mt], bh[nt], acc[mt][nt], 0, 0, 0);
            }
        __syncthreads();
    }
}

// ---- layer 1: z1 = x@W1^T + b1 -> dist1, m1and, h1 hi/lo -------------------
__global__ __launch_bounds__(256) void k_l1(
    const unsigned short* __restrict__ xhi,  const unsigned short* __restrict__ xlo,
    const unsigned short* __restrict__ W1hi, const unsigned short* __restrict__ W1lo,
    const float* __restrict__ b1, const float* __restrict__ rn1,
    float* __restrict__ dists, unsigned short* __restrict__ m1and,
    unsigned short* __restrict__ h1hi, unsigned short* __restrict__ h1lo) {
    __shared__ __align__(16) unsigned short sm[8192];
    int m0 = blockIdx.x * 64, n0 = blockIdx.y * 64;
    f32x4 acc[2][2] = {};
    mfma3_64<D>(xhi, xlo, W1hi, W1lo, m0, n0, sm, acc);
    int l = threadIdx.x & 63, w = threadIdx.x >> 6;
    int quad = l >> 4, l16 = l & 15;
    int wm = (w >> 1) * 32, wn = (w & 1) * 32;
    #pragma unroll
    for (int mt = 0; mt < 2; mt++)
        #pragma unroll
        for (int nt = 0; nt < 2; nt++) {
            int n = n0 + wn + nt * 16 + l16;
            float bv = b1[n], rv = rn1[n];
            #pragma unroll
            for (int r = 0; r < 4; r++) {
                int m = m0 + wm + mt * 16 + quad * 4 + r;
                float z = acc[mt][nt][r] + bv;
                dists[(size_t)m * NDIST + n] = fabsf(z) / rv;
                size_t idx = (size_t)m * D1 + n;
                m1and[idx] = (z > 0.f) ? 0xFFFFu : 0u;
                float h = z > 0.f ? z : 0.f;
                unsigned short hh = f2bf(h);
                h1hi[idx] = hh;
                h1lo[idx] = f2bf(h - bf2f(hh));
            }
        }
}

// ---- layer 2: z2 = h1@W2^T + b2 -> z2, h2 hi/lo ----------------------------
__global__ __launch_bounds__(256) void k_l2(
    const unsigned short* __restrict__ h1hi, const unsigned short* __restrict__ h1lo,
    const unsigned short* __restrict__ W2hi, const unsigned short* __restrict__ W2lo,
    const float* __restrict__ b2, float* __restrict__ z2,
    unsigned short* __restrict__ h2hi, unsigned short* __restrict__ h2lo) {
    __shared__ __align__(16) unsigned short sm[8192];
    int m0 = blockIdx.x * 64, n0 = blockIdx.y * 64;
    f32x4 acc[2][2] = {};
    mfma3_64<D1>(h1hi, h1lo, W2hi, W2lo, m0, n0, sm, acc);
    int l = threadIdx.x & 63, w = threadIdx.x >> 6;
    int quad = l >> 4, l16 = l & 15;
    int wm = (w >> 1) * 32, wn = (w & 1) * 32;
    #pragma unroll
    for (int mt = 0; mt < 2; mt++)
        #pragma unroll
        for (int nt = 0; nt < 2; nt++) {
            int n = n0 + wn + nt * 16 + l16;
            float bv = b2[n];
            #pragma unroll
            for (int r = 0; r < 4; r++) {
                int m = m0 + wm + mt * 16 + quad * 4 + r;
                float z = acc[mt][nt][r] + bv;
                size_t idx = (size_t)m * D2 + n;
                z2[idx] = z;
                float h = z > 0.f ? z : 0.f;
                unsigned short hh = f2bf(h);
                h2hi[idx] = hh;
                h2lo[idx] = f2bf(h - bf2f(hh));
            }
        }
}

// ---- layer 3: z3 = h2@W3^T + b3 -------------------------------------------
__global__ __launch_bounds__(256) void k_l3(
    const unsigned short* __restrict__ h2hi, const unsigned short* __restrict__ h2lo,
    const unsigned short* __restrict__ W3hi, const unsigned short* __restrict__ W3lo,
    const float* __restrict__ b3, float* __restrict__ z3) {
    __shared__ __align__(16) unsigned short sm[8192];
    int m0 = blockIdx.x * 64, n0 = blockIdx.y * 64;
    f32x4 acc[2][2] = {};
    mfma3_64<D2>(h2hi, h2lo, W3hi, W3lo, m0, n0, sm, acc);
    int l = threadIdx.x & 63, w = threadIdx.x >> 6;
    int quad = l >> 4, l16 = l & 15;
    int wm = (w >> 1) * 32, wn = (w & 1) * 32;
    #pragma unroll
    for (int mt = 0; mt < 2; mt++)
        #pragma unroll
        for (int nt = 0; nt < 2; nt++) {
            int n = n0 + wn + nt * 16 + l16;
            float bv = b3[n];
            #pragma unroll
            for (int r = 0; r < 4; r++) {
                int m = m0 + wm + mt * 16 + quad * 4 + r;
                z3[(size_t)m * D3 + n] = acc[mt][nt][r] + bv;
            }
        }
}

// ---- GEMM1: V2T[d][o] = sum_i (m1 & W1T)[d][i] * W2[o][i] ------------------
// 128x128 tile, BK=32, both operands via global_load_lds; mask on A fragments.
// Epilogue: atomic norm2 (pre-m2), LDS-transpose + coalesced m2-masked bf16 store.
__global__ __launch_bounds__(256) void k_gemm1(
    const unsigned short* __restrict__ W1T,    // [256][1024]
    const unsigned short* __restrict__ W2b,    // [512][1024] (= W2hi)
    const unsigned short* __restrict__ m1and,  // [B][1024]
    const float* __restrict__ z2,              // [B][512]
    unsigned short* __restrict__ V2mT,         // [CH][256][512]
    float* __restrict__ norm2,                 // [B][512]
    int b0) {
    __shared__ __align__(16) unsigned short sm[128 * 136];  // 34816 B; loop uses first 8192 us
    unsigned short* As = sm;          // 128*32
    unsigned short* Bs = sm + 4096;   // 128*32
    int m0 = blockIdx.x * 128;        // d
    int o0 = blockIdx.y * 128;        // o
    int bc = blockIdx.z;
    int b = b0 + bc;
    int tid = threadIdx.x;
    int l = tid & 63, w = tid >> 6;
    int rsub = l >> 2, cq = l & 3;
    int quad = l >> 4, l16 = l & 15;
    int wm = (w >> 1) * 64, wn = (w & 1) * 64;
    const unsigned short* mrow = m1and + (size_t)b * D1;

    f32x4 acc[4][4];
    #pragma unroll
    for (int i = 0; i < 4; i++)
        #pragma unroll
        for (int j = 0; j < 4; j++) acc[i][j] = (f32x4)0.f;

    for (int kk = 0; kk < D1; kk += 32) {
        #pragma unroll
        for (int r = 0; r < 2; r++) {
            int ii = w * 2 + r;
            gld16(W1T + (size_t)(m0 + ii * 16 + rsub) * D1 + kk + cq * 8, As + ii * 512);
            gld16(W2b + (size_t)(o0 + ii * 16 + rsub) * D1 + kk + cq * 8, Bs + ii * 512);
        }
        uint4 mv = *(const uint4*)(mrow + kk + quad * 8);
        __syncthreads();
        short8 a[4], bf[4];
        #pragma unroll
        for (int mt = 0; mt < 4; mt++) {
            uint4 av = *(const uint4*)(As + (wm + mt * 16 + l16) * 32 + quad * 8);
            av.x &= mv.x; av.y &= mv.y; av.z &= mv.z; av.w &= mv.w;
            a[mt] = as_s8(av);
        }
        #pragma unroll
        for (int nt = 0; nt < 4; nt++)
            bf[nt] = *(const short8*)(Bs + (wn + nt * 16 + l16) * 32 + quad * 8);
        #pragma unroll
        for (int mt = 0; mt < 4; mt++)
            #pragma unroll
            for (int nt = 0; nt < 4; nt++)
                acc[mt][nt] = __builtin_amdgcn_mfma_f32_16x16x32_bf16(
                    a[mt], bf[nt], acc[mt][nt], 0, 0, 0);
        __syncthreads();
    }

    // norm2 (pre-m2 mask)
    #pragma unroll
    for (int nt = 0; nt < 4; nt++) {
        float s = 0.f;
        #pragma unroll
        for (int mt = 0; mt < 4; mt++)
            #pragma unroll
            for (int r = 0; r < 4; r++) { float v = acc[mt][nt][r]; s += v * v; }
        s += __shfl_down(s, 32, 64);
        s += __shfl_down(s, 16, 64);
        if (l < 16)
            atomicAdd(&norm2[(size_t)b * D2 + o0 + wn + nt * 16 + l], s);
    }

    // m2-masked bf16, LDS transpose, coalesced store
    float z2v[4];
    #pragma unroll
    for (int nt = 0; nt < 4; nt++)
        z2v[nt] = z2[(size_t)b * D2 + o0 + wn + nt * 16 + l16];
    unsigned short* Ts = sm;   // [128][136]
    #pragma unroll
    for (int mt = 0; mt < 4; mt++)
        #pragma unroll
        for (int r = 0; r < 4; r++) {
            int dl = wm + mt * 16 + quad * 4 + r;
            #pragma unroll
            for (int nt = 0; nt < 4; nt++) {
                int ol = wn + nt * 16 + l16;
                float v = (z2v[nt] > 0.f) ? acc[mt][nt][r] : 0.f;
                Ts[dl * 136 + ol] = f2bf(v);
            }
        }
    __syncthreads();
    int dl = tid >> 1, half = tid & 1;
    unsigned short* dst = V2mT + (size_t)bc * (D * D2) + (size_t)(m0 + dl) * D2 + o0 + half * 64;
    const unsigned short* srcp = Ts + dl * 136 + half * 64;
    #pragma unroll
    for (int j = 0; j < 8; j++)
        *(uint4*)(dst + j * 8) = *(const uint4*)(srcp + j * 8);
}

// ---- GEMM2: norm3[b][p] += sum_d (sum_o W3[p][o] * V2mT[d][o])^2 -----------
// Tile 256(p) x 128(d), K=512. A=W3hi, B=V2mT slab, both via global_load_lds.
__global__ __launch_bounds__(256, 1) void k_gemm2(
    const unsigned short* __restrict__ W3b,    // [256][512] (= W3hi)
    const unsigned short* __restrict__ V2mT,   // [CH][256][512]
    float* __restrict__ norm3,                 // [B][256]
    int b0) {
    __shared__ __align__(16) unsigned short sm[12288];  // As 256x32 + Bs 128x32
    unsigned short* As = sm;
    unsigned short* Bs = sm + 8192;
    int n0 = blockIdx.x * 128;   // d-tile
    int bc = blockIdx.y;
    int b = b0 + bc;
    int tid = threadIdx.x;
    int l = tid & 63, w = tid >> 6;
    int rsub = l >> 2, cq = l & 3;
    int quad = l >> 4, l16 = l & 15;
    int wm = w * 64;
    const unsigned short* Bsrc = V2mT + (size_t)bc * (D * D2);

    f32x4 acc[4][8];
    #pragma unroll
    for (int i = 0; i < 4; i++)
        #pragma unroll
        for (int j = 0; j < 8; j++) acc[i][j] = (f32x4)0.f;

    for (int kk = 0; kk < D2; kk += 32) {
        #pragma unroll
        for (int r = 0; r < 4; r++) {
            int ii = w * 4 + r;
            gld16(W3b + (size_t)(ii * 16 + rsub) * D2 + kk + cq * 8, As + ii * 512);
        }
        #pragma unroll
        for (int r = 0; r < 2; r++) {
            int ii = w * 2 + r;
            gld16(Bsrc + (size_t)(n0 + ii * 16 + rsub) * D2 + kk + cq * 8, Bs + ii * 512);
        }
        __syncthreads();
        short8 a[4], bf[8];
        #pragma unroll
        for (int mt = 0; mt < 4; mt++)
            a[mt] = *(const short8*)(As + (wm + mt * 16 + l16) * 32 + quad * 8);
        #pragma unroll
        for (int nt = 0; nt < 8; nt++)
            bf[nt] = *(const short8*)(Bs + (nt * 16 + l16) * 32 + quad * 8);
        #pragma unroll
        for (int mt = 0; mt < 4; mt++)
            #pragma unroll
            for (int nt = 0; nt < 8; nt++)
                acc[mt][nt] = __builtin_amdgcn_mfma_f32_16x16x32_bf16(
                    a[mt], bf[nt], acc[mt][nt], 0, 0, 0);
        __syncthreads();
    }

    #pragma unroll
    for (int mt = 0; mt < 4; mt++)
        #pragma unroll
        for (int r = 0; r < 4; r++) {
            float s = 0.f;
            #pragma unroll
            for (int nt = 0; nt < 8; nt++) { float v = acc[mt][nt][r]; s += v * v; }
            s += __shfl_down(s, 8, 64);
            s += __shfl_down(s, 4, 64);
            s += __shfl_down(s, 2, 64);
            s += __shfl_down(s, 1, 64);
            if (l16 == 0)
                atomicAdd(&norm3[(size_t)b * D3 + wm + mt * 16 + quad * 4 + r], s);
        }
}

// ---- dist2 + dist3 ---------------------------------------------------------
__global__ __launch_bounds__(256) void k_dist23(
    const float* __restrict__ z2, const float* __restrict__ z3,
    const float* __restrict__ norm2, const float* __restrict__ norm3,
    float* __restrict__ dists) {
    int i = blockIdx.x * 256 + threadIdx.x;
    if (i < B * D2) {
        int b = i >> 9, o = i & (D2 - 1);
        dists[(size_t)b * NDIST + D1 + o] = fabsf(z2[i]) / sqrtf(norm2[i]);
    } else {
        int j = i - B * D2;
        int b = j >> 8, p = j & (D3 - 1);
        dists[(size_t)b * NDIST + D1 + D2 + p] = fabsf(z3[j]) / sqrtf(norm3[j]);
    }
}

// ---- per-batch k-smallest sum (register-resident, 7 elems/thread) ----------
__global__ __launch_bounds__(256) void k_topk(const float* __restrict__ dists,
                                              const int* __restrict__ kp,
                                              float* __restrict__ partial) {
    __shared__ unsigned long long wmin[4];
    int b = blockIdx.x, t = threadIdx.x;
    float lv[7];
    #pragma unroll
    for (int j = 0; j < 7; j++) lv[j] = dists[(size_t)b * NDIST + t + 256 * j];
    int k = *kp;
    if (k > NDIST) k = NDIST;
    float sum = 0.f;
    for (int it = 0; it < k; it++) {
        float mv = lv[0]; int mj = 0;
        #pragma unroll
        for (int j = 1; j < 7; j++)
            if (lv[j] < mv) { mv = lv[j]; mj = j; }
        unsigned long long key =
            ((unsigned long long)__float_as_uint(mv) << 32) | (unsigned)(t * 8 + mj);
        #pragma unroll
        for (int off = 32; off > 0; off >>= 1) {
            unsigned long long o = __shfl_down(key, off, 64);
            if (o < key) key = o;
        }
        if ((t & 63) == 0) wmin[t >> 6] = key;
        __syncthreads();
        unsigned long long k0 = wmin[0];
        #pragma unroll
        for (int ww = 1; ww < 4; ww++) if (wmin[ww] < k0) k0 = wmin[ww];
        sum += __uint_as_float((unsigned)(k0 >> 32));
        int wt = (int)((k0 & 0xFFFu) >> 3), wj = (int)(k0 & 7u);
        if (t == wt) lv[wj] = FLT_MAX;
        __syncthreads();
    }
    if (t == 0) partial[b] = sum;
}

// ---- final reduce ----------------------------------------------------------
__global__ __launch_bounds__(256) void k_final(const float* __restrict__ partial,
                                               float* __restrict__ out) {
    __shared__ float s[4];
    int t = threadIdx.x;
    float v = (t < B) ? partial[t] : 0.f;
    v = waveReduceSum(v);
    if ((t & 63) == 0) s[t >> 6] = v;
    __syncthreads();
    if (t == 0) out[0] = s[0] + s[1] + s[2] + s[3];
}

extern "C" void kernel_launch(void* const* d_in, const int* in_sizes, int n_in,
                              void* d_out, int out_size, void* d_ws, size_t ws_size,
                              hipStream_t stream) {
    const float* x  = (const float*)d_in[0];
    const float* W1 = (const float*)d_in[1];
    const float* b1 = (const float*)d_in[2];
    const float* W2 = (const float*)d_in[3];
    const float* b2 = (const float*)d_in[4];
    const float* W3 = (const float*)d_in[5];
    const float* b3 = (const float*)d_in[6];
    const int*   kp = (const int*)d_in[7];
    float* outp = (float*)d_out;

    // ---- workspace layout ----
    float* fp = (float*)d_ws;
    float* rn1     = fp;                          fp += D1;
    float* z2      = fp;                          fp += (size_t)B * D2;
    float* z3      = fp;                          fp += (size_t)B * D3;
    float* dists   = fp;                          fp += (size_t)B * NDIST;
    float* partial = fp;                          fp += 256;
    float* norm2   = fp;                          fp += (size_t)B * D2;   // norm2,norm3 contiguous
    float* norm3   = fp;                          fp += (size_t)B * D3;
    unsigned short* up = (unsigned short*)fp;
    unsigned short* W1T   = up;  up += (size_t)D * D1;
    unsigned short* W2hi  = up;  up += (size_t)D2 * D1;
    unsigned short* W2lo  = up;  up += (size_t)D2 * D1;
    unsigned short* W3hi  = up;  up += (size_t)D3 * D2;
    unsigned short* W3lo  = up;  up += (size_t)D3 * D2;
    unsigned short* xhi   = up;  up += (size_t)B * D;
    unsigned short* xlo   = up;  up += (size_t)B * D;
    unsigned short* W1hi  = up;  up += (size_t)D1 * D;
    unsigned short* W1lo  = up;  up += (size_t)D1 * D;
    unsigned short* h1hi  = up;  up += (size_t)B * D1;
    unsigned short* h1lo  = up;  up += (size_t)B * D1;
    unsigned short* h2hi  = up;  up += (size_t)B * D2;
    unsigned short* h2lo  = up;  up += (size_t)B * D2;
    unsigned short* m1and = up;  up += (size_t)B * D1;
    unsigned short* V2mT  = up;

    size_t base_bytes = (size_t)((char*)V2mT - (char*)d_ws);
    int CH = 8;
    const int cands[6] = {256, 128, 64, 32, 16, 8};
    for (int c = 0; c < 6; c++) {
        size_t need = base_bytes + (size_t)cands[c] * D * D2 * sizeof(unsigned short);
        if (need <= ws_size) { CH = cands[c]; break; }
    }

    k_zero<<<(B * D2 + B * D3) / 256, 256, 0, stream>>>(norm2, B * D2 + B * D3);
    k_cvtall<<<960, 256, 0, stream>>>(x, W1, W2, W3, xhi, xlo, W1hi, W1lo,
                                      W2hi, W2lo, W3hi, W3lo);
    k_w1t<<<dim3(D1 / 32, D / 32), 256, 0, stream>>>(W1, W1T);
    k_rn1<<<D1 / 4, 256, 0, stream>>>(W1, rn1);

    k_l1<<<dim3(B / 64, D1 / 64), 256, 0, stream>>>(xhi, xlo, W1hi, W1lo, b1, rn1,
                                                    dists, m1and, h1hi, h1lo);
    k_l2<<<dim3(B / 64, D2 / 64), 256, 0, stream>>>(h1hi, h1lo, W2hi, W2lo, b2,
                                                    z2, h2hi, h2lo);
    k_l3<<<dim3(B / 64, D3 / 64), 256, 0, stream>>>(h2hi, h2lo, W3hi, W3lo, b3, z3);

    for (int b0 = 0; b0 < B; b0 += CH) {
        k_gemm1<<<dim3(D / 128, D2 / 128, CH), 256, 0, stream>>>(
            W1T, W2hi, m1and, z2, V2mT, norm2, b0);
        k_gemm2<<<dim3(D / 128, CH), 256, 0, stream>>>(W3hi, V2mT, norm3, b0);
    }

    k_dist23<<<(B * D2 + B * D3) / 256, 256, 0, stream>>>(z2, z3, norm2, norm3, dists);
    k_topk<<<B, 256, 0, stream>>>(dists, kp, partial);
    k_final<<<1, 256, 0, stream>>>(partial, outp);
}

// Round 4
// 281.998 us; speedup vs baseline: 10.1471x; 1.0676x over previous
//
#include <hip/hip_runtime.h>
#include <math.h>
#include <float.h>

#define B   256
#define D   256
#define D1  1024
#define D2  512
#define D3  256
#define NDIST (D1 + D2 + D3)   // 1792

typedef __attribute__((ext_vector_type(8))) short short8;
typedef __attribute__((ext_vector_type(4))) float f32x4;

__device__ __forceinline__ float waveReduceSum(float v) {
    #pragma unroll
    for (int off = 32; off > 0; off >>= 1)
        v += __shfl_down(v, off, 64);
    return v;
}

__device__ __forceinline__ unsigned short f2bf(float f) {
    unsigned int u = __float_as_uint(f);
    u = (u + 0x7FFFu + ((u >> 16) & 1u)) >> 16;   // RNE
    return (unsigned short)u;
}
__device__ __forceinline__ float bf2f(unsigned short h) {
    return __uint_as_float(((unsigned int)h) << 16);
}
__device__ __forceinline__ short8 as_s8(uint4 v) {
    union { uint4 u; short8 s; } c; c.u = v; return c.s;
}
__device__ __forceinline__ void gld16(const void* g, void* l) {
    __builtin_amdgcn_global_load_lds(
        (const __attribute__((address_space(1))) unsigned int*)g,
        (__attribute__((address_space(3))) unsigned int*)l, 16, 0, 0);
}

// LDS bank-conflict swizzle for BK=32-ushort tiles staged via global_load_lds.
// Slot s of LDS row r holds global k-chunk c = (s + h(r)) & 3, h(r) = (r>>1)&3.
// Fragment read for quad q: slot (q - h(r)) & 3  ->  2 lanes/bank (free).
__device__ __forceinline__ int swz_src(int row, int lane) {
    return ((lane & 3) + ((row >> 1) & 3)) & 3;
}
__device__ __forceinline__ int swz_frag(int row, int quad) {
    return row * 32 + (((quad - ((row >> 1) & 3)) & 3) * 8);
}

// ---- zero helper -----------------------------------------------------------
__global__ __launch_bounds__(256) void k_zero(float* __restrict__ p, int n) {
    int i = blockIdx.x * 256 + threadIdx.x;
    if (i < n) p[i] = 0.f;
}

// ---- hi/lo split of x, W1, W2, W3 in one dispatch --------------------------
__global__ __launch_bounds__(256) void k_cvtall(
    const float* __restrict__ x,  const float* __restrict__ W1,
    const float* __restrict__ W2, const float* __restrict__ W3,
    unsigned short* __restrict__ xhi,  unsigned short* __restrict__ xlo,
    unsigned short* __restrict__ W1hi, unsigned short* __restrict__ W1lo,
    unsigned short* __restrict__ W2hi, unsigned short* __restrict__ W2lo,
    unsigned short* __restrict__ W3hi, unsigned short* __restrict__ W3lo) {
    int i4 = (blockIdx.x * 256 + threadIdx.x) * 4;
    const float* src; unsigned short *hi, *lo; int off;
    if (i4 < 65536)       { src = x;  hi = xhi;  lo = xlo;  off = i4; }
    else if (i4 < 327680) { src = W1; hi = W1hi; lo = W1lo; off = i4 - 65536; }
    else if (i4 < 851968) { src = W2; hi = W2hi; lo = W2lo; off = i4 - 327680; }
    else                  { src = W3; hi = W3hi; lo = W3lo; off = i4 - 851968; }
    float4 v = *(const float4*)(src + off);
    ushort4 h, l;
    h.x = f2bf(v.x); l.x = f2bf(v.x - bf2f(h.x));
    h.y = f2bf(v.y); l.y = f2bf(v.y - bf2f(h.y));
    h.z = f2bf(v.z); l.z = f2bf(v.z - bf2f(h.z));
    h.w = f2bf(v.w); l.w = f2bf(v.w - bf2f(h.w));
    *(ushort4*)(hi + off) = h;
    *(ushort4*)(lo + off) = l;
}

// ---- W1 [1024][256] fp32 -> W1T [256][1024] bf16 ---------------------------
__global__ __launch_bounds__(256) void k_w1t(const float* __restrict__ W1,
                                             unsigned short* __restrict__ W1T) {
    __shared__ float tile[32][33];
    int i0 = blockIdx.x * 32;
    int d0 = blockIdx.y * 32;
    int tx = threadIdx.x & 31, ty = threadIdx.x >> 5;
    #pragma unroll
    for (int r = 0; r < 32; r += 8)
        tile[ty + r][tx] = W1[(size_t)(i0 + ty + r) * D + d0 + tx];
    __syncthreads();
    #pragma unroll
    for (int r = 0; r < 32; r += 8)
        W1T[(size_t)(d0 + ty + r) * D1 + i0 + tx] = f2bf(tile[tx][ty + r]);
}

// ---- W1 row norms ----------------------------------------------------------
__global__ __launch_bounds__(256) void k_rn1(const float* __restrict__ W1,
                                             float* __restrict__ rn1) {
    int gw = (blockIdx.x * blockDim.x + threadIdx.x) >> 6;
    int lane = threadIdx.x & 63;
    if (gw >= D1) return;
    const float* row = W1 + (size_t)gw * D;
    float s = 0.f;
    for (int t = lane; t < D; t += 64) { float v = row[t]; s += v * v; }
    s = waveReduceSum(s);
    if (lane == 0) rn1[gw] = sqrtf(s);
}

// ---- compensated bf16 MFMA mainloop for a 64x64 tile, C = A @ B^T ----------
template <int KD>
__device__ __forceinline__ void mfma3_64(
    const unsigned short* __restrict__ Ahi, const unsigned short* __restrict__ Alo,
    const unsigned short* __restrict__ Bhi, const unsigned short* __restrict__ Blo,
    int m0, int n0, unsigned short* sm, f32x4 acc[2][2]) {
    int tid = threadIdx.x;
    int l = tid & 63, w = tid >> 6;
    int rsub = l >> 2;
    int quad = l >> 4, l16 = l & 15;
    int wm = (w >> 1) * 32, wn = (w & 1) * 32;
    unsigned short* sAh = sm;
    unsigned short* sAl = sm + 2048;
    unsigned short* sBh = sm + 4096;
    unsigned short* sBl = sm + 6144;
    ptrdiff_t dA = Alo - Ahi, dB = Blo - Bhi;
    int rloc = w * 16 + rsub;                    // LDS-local staged row
    int c = swz_src(rloc, l);
    const unsigned short* pa = Ahi + (size_t)(m0 + rloc) * KD + c * 8;
    const unsigned short* pb = Bhi + (size_t)(n0 + rloc) * KD + c * 8;
    int aoff[2], boff[2];
    #pragma unroll
    for (int mt = 0; mt < 2; mt++) aoff[mt] = swz_frag(wm + mt * 16 + l16, quad);
    #pragma unroll
    for (int nt = 0; nt < 2; nt++) boff[nt] = swz_frag(wn + nt * 16 + l16, quad);
    for (int kk = 0; kk < KD; kk += 32) {
        gld16(pa + kk,      sAh + w * 512);
        gld16(pa + dA + kk, sAl + w * 512);
        gld16(pb + kk,      sBh + w * 512);
        gld16(pb + dB + kk, sBl + w * 512);
        __syncthreads();
        short8 ah[2], al[2], bh[2], bl[2];
        #pragma unroll
        for (int mt = 0; mt < 2; mt++) {
            ah[mt] = *(const short8*)(sAh + aoff[mt]);
            al[mt] = *(const short8*)(sAl + aoff[mt]);
        }
        #pragma unroll
        for (int nt = 0; nt < 2; nt++) {
            bh[nt] = *(const short8*)(sBh + boff[nt]);
            bl[nt] = *(const short8*)(sBl + boff[nt]);
        }
        #pragma unroll
        for (int mt = 0; mt < 2; mt++)
            #pragma unroll
            for (int nt = 0; nt < 2; nt++) {
                acc[mt][nt] = __builtin_amdgcn_mfma_f32_16x16x32_bf16(ah[mt], bh[nt], acc[mt][nt], 0, 0, 0);
                acc[mt][nt] = __builtin_amdgcn_mfma_f32_16x16x32_bf16(ah[mt], bl[nt], acc[mt][nt], 0, 0, 0);
                acc[mt][nt] = __builtin_amdgcn_mfma_f32_16x16x32_bf16(al[mt], bh[nt], acc[mt][nt], 0, 0, 0);
            }
        __syncthreads();
    }
}

// ---- layer 1 ---------------------------------------------------------------
__global__ __launch_bounds__(256) void k_l1(
    const unsigned short* __restrict__ xhi,  const unsigned short* __restrict__ xlo,
    const unsigned short* __restrict__ W1hi, const unsigned short* __restrict__ W1lo,
    const float* __restrict__ b1, const float* __restrict__ rn1,
    float* __restrict__ dists, unsigned short* __restrict__ m1and,
    unsigned short* __restrict__ h1hi, unsigned short* __restrict__ h1lo) {
    __shared__ __align__(16) unsigned short sm[8192];
    int m0 = blockIdx.x * 64, n0 = blockIdx.y * 64;
    f32x4 acc[2][2] = {};
    mfma3_64<D>(xhi, xlo, W1hi, W1lo, m0, n0, sm, acc);
    int l = threadIdx.x & 63, w = threadIdx.x >> 6;
    int quad = l >> 4, l16 = l & 15;
    int wm = (w >> 1) * 32, wn = (w & 1) * 32;
    #pragma unroll
    for (int mt = 0; mt < 2; mt++)
        #pragma unroll
        for (int nt = 0; nt < 2; nt++) {
            int n = n0 + wn + nt * 16 + l16;
            float bv = b1[n], rv = rn1[n];
            #pragma unroll
            for (int r = 0; r < 4; r++) {
                int m = m0 + wm + mt * 16 + quad * 4 + r;
                float z = acc[mt][nt][r] + bv;
                dists[(size_t)m * NDIST + n] = fabsf(z) / rv;
                size_t idx = (size_t)m * D1 + n;
                m1and[idx] = (z > 0.f) ? 0xFFFFu : 0u;
                float h = z > 0.f ? z : 0.f;
                unsigned short hh = f2bf(h);
                h1hi[idx] = hh;
                h1lo[idx] = f2bf(h - bf2f(hh));
            }
        }
}

// ---- layer 2 ---------------------------------------------------------------
__global__ __launch_bounds__(256) void k_l2(
    const unsigned short* __restrict__ h1hi, const unsigned short* __restrict__ h1lo,
    const unsigned short* __restrict__ W2hi, const unsigned short* __restrict__ W2lo,
    const float* __restrict__ b2, float* __restrict__ z2,
    unsigned short* __restrict__ h2hi, unsigned short* __restrict__ h2lo) {
    __shared__ __align__(16) unsigned short sm[8192];
    int m0 = blockIdx.x * 64, n0 = blockIdx.y * 64;
    f32x4 acc[2][2] = {};
    mfma3_64<D1>(h1hi, h1lo, W2hi, W2lo, m0, n0, sm, acc);
    int l = threadIdx.x & 63, w = threadIdx.x >> 6;
    int quad = l >> 4, l16 = l & 15;
    int wm = (w >> 1) * 32, wn = (w & 1) * 32;
    #pragma unroll
    for (int mt = 0; mt < 2; mt++)
        #pragma unroll
        for (int nt = 0; nt < 2; nt++) {
            int n = n0 + wn + nt * 16 + l16;
            float bv = b2[n];
            #pragma unroll
            for (int r = 0; r < 4; r++) {
                int m = m0 + wm + mt * 16 + quad * 4 + r;
                float z = acc[mt][nt][r] + bv;
                size_t idx = (size_t)m * D2 + n;
                z2[idx] = z;
                float h = z > 0.f ? z : 0.f;
                unsigned short hh = f2bf(h);
                h2hi[idx] = hh;
                h2lo[idx] = f2bf(h - bf2f(hh));
            }
        }
}

// ---- layer 3 ---------------------------------------------------------------
__global__ __launch_bounds__(256) void k_l3(
    const unsigned short* __restrict__ h2hi, const unsigned short* __restrict__ h2lo,
    const unsigned short* __restrict__ W3hi, const unsigned short* __restrict__ W3lo,
    const float* __restrict__ b3, float* __restrict__ z3) {
    __shared__ __align__(16) unsigned short sm[8192];
    int m0 = blockIdx.x * 64, n0 = blockIdx.y * 64;
    f32x4 acc[2][2] = {};
    mfma3_64<D2>(h2hi, h2lo, W3hi, W3lo, m0, n0, sm, acc);
    int l = threadIdx.x & 63, w = threadIdx.x >> 6;
    int quad = l >> 4, l16 = l & 15;
    int wm = (w >> 1) * 32, wn = (w & 1) * 32;
    #pragma unroll
    for (int mt = 0; mt < 2; mt++)
        #pragma unroll
        for (int nt = 0; nt < 2; nt++) {
            int n = n0 + wn + nt * 16 + l16;
            float bv = b3[n];
            #pragma unroll
            for (int r = 0; r < 4; r++) {
                int m = m0 + wm + mt * 16 + quad * 4 + r;
                z3[(size_t)m * D3 + n] = acc[mt][nt][r] + bv;
            }
        }
}

// ---- GEMM1: V2T[d][o] = sum_i (m1 & W1T)[d][i] * W2[o][i] ------------------
// 128x128 tile, BK=32, swizzled staging; mask on A fragments; direct store.
__global__ __launch_bounds__(256) void k_gemm1(
    const unsigned short* __restrict__ W1T,    // [256][1024]
    const unsigned short* __restrict__ W2b,    // [512][1024] (= W2hi)
    const unsigned short* __restrict__ m1and,  // [B][1024]
    const float* __restrict__ z2,              // [B][512]
    unsigned short* __restrict__ V2mT,         // [CH][256][512]
    float* __restrict__ norm2,                 // [B][512]
    int b0) {
    __shared__ __align__(16) unsigned short As[4096];
    __shared__ __align__(16) unsigned short Bs[4096];
    int m0 = blockIdx.x * 128;        // d
    int o0 = blockIdx.y * 128;        // o
    int bc = blockIdx.z;
    int b = b0 + bc;
    int tid = threadIdx.x;
    int l = tid & 63, w = tid >> 6;
    int rsub = l >> 2;
    int quad = l >> 4, l16 = l & 15;
    int wm = (w >> 1) * 64, wn = (w & 1) * 64;
    const unsigned short* mrow = m1and + (size_t)b * D1;

    const unsigned short* pa[2];
    const unsigned short* pb[2];
    #pragma unroll
    for (int r = 0; r < 2; r++) {
        int ii = w * 2 + r;
        int rloc = ii * 16 + rsub;               // LDS-local row 0..127
        int c = swz_src(rloc, l);
        pa[r] = W1T + (size_t)(m0 + rloc) * D1 + c * 8;
        pb[r] = W2b + (size_t)(o0 + rloc) * D1 + c * 8;
    }
    int aoff[4], boff[4];
    #pragma unroll
    for (int mt = 0; mt < 4; mt++) aoff[mt] = swz_frag(wm + mt * 16 + l16, quad);
    #pragma unroll
    for (int nt = 0; nt < 4; nt++) boff[nt] = swz_frag(wn + nt * 16 + l16, quad);

    f32x4 acc[4][4];
    #pragma unroll
    for (int i = 0; i < 4; i++)
        #pragma unroll
        for (int j = 0; j < 4; j++) acc[i][j] = (f32x4)0.f;

    for (int kk = 0; kk < D1; kk += 32) {
        #pragma unroll
        for (int r = 0; r < 2; r++) {
            int ii = w * 2 + r;
            gld16(pa[r] + kk, As + ii * 512);
            gld16(pb[r] + kk, Bs + ii * 512);
        }
        uint4 mv = *(const uint4*)(mrow + kk + quad * 8);
        __syncthreads();
        short8 a[4], bf[4];
        #pragma unroll
        for (int mt = 0; mt < 4; mt++) {
            uint4 av = *(const uint4*)(As + aoff[mt]);
            av.x &= mv.x; av.y &= mv.y; av.z &= mv.z; av.w &= mv.w;
            a[mt] = as_s8(av);
        }
        #pragma unroll
        for (int nt = 0; nt < 4; nt++)
            bf[nt] = *(const short8*)(Bs + boff[nt]);
        #pragma unroll
        for (int mt = 0; mt < 4; mt++)
            #pragma unroll
            for (int nt = 0; nt < 4; nt++)
                acc[mt][nt] = __builtin_amdgcn_mfma_f32_16x16x32_bf16(
                    a[mt], bf[nt], acc[mt][nt], 0, 0, 0);
        __syncthreads();
    }

    // norm2 (pre-m2 mask)
    #pragma unroll
    for (int nt = 0; nt < 4; nt++) {
        float s = 0.f;
        #pragma unroll
        for (int mt = 0; mt < 4; mt++)
            #pragma unroll
            for (int r = 0; r < 4; r++) { float v = acc[mt][nt][r]; s += v * v; }
        s += __shfl_down(s, 32, 64);
        s += __shfl_down(s, 16, 64);
        if (l < 16)
            atomicAdd(&norm2[(size_t)b * D2 + o0 + wn + nt * 16 + l], s);
    }

    // m2-masked bf16 direct store (scattered 2B; HBM is <8% utilized)
    float z2v[4];
    #pragma unroll
    for (int nt = 0; nt < 4; nt++)
        z2v[nt] = z2[(size_t)b * D2 + o0 + wn + nt * 16 + l16];
    unsigned short* outb = V2mT + (size_t)bc * (D * D2);
    #pragma unroll
    for (int mt = 0; mt < 4; mt++) {
        int dbase = m0 + wm + mt * 16 + quad * 4;
        #pragma unroll
        for (int r = 0; r < 4; r++)
            #pragma unroll
            for (int nt = 0; nt < 4; nt++) {
                int o = o0 + wn + nt * 16 + l16;
                float v = (z2v[nt] > 0.f) ? acc[mt][nt][r] : 0.f;
                outb[(size_t)(dbase + r) * D2 + o] = f2bf(v);
            }
    }
}

// ---- GEMM2: norm3[b][p] += sum_d (sum_o W3[p][o] * V2mT[d][o])^2 -----------
// Tile 256(p) x 128(d), K=512, swizzled staging both sides.
__global__ __launch_bounds__(256, 1) void k_gemm2(
    const unsigned short* __restrict__ W3b,    // [256][512] (= W3hi)
    const unsigned short* __restrict__ V2mT,   // [CH][256][512]
    float* __restrict__ norm3,                 // [B][256]
    int b0) {
    __shared__ __align__(16) unsigned short As[8192];   // 256x32
    __shared__ __align__(16) unsigned short Bs[4096];   // 128x32
    int n0 = blockIdx.x * 128;   // d-tile
    int bc = blockIdx.y;
    int b = b0 + bc;
    int tid = threadIdx.x;
    int l = tid & 63, w = tid >> 6;
    int rsub = l >> 2;
    int quad = l >> 4, l16 = l & 15;
    int wm = w * 64;
    const unsigned short* Bsrc = V2mT + (size_t)bc * (D * D2);

    const unsigned short* pa[4];
    #pragma unroll
    for (int r = 0; r < 4; r++) {
        int ii = w * 4 + r;
        int rloc = ii * 16 + rsub;               // 0..255
        int c = swz_src(rloc, l);
        pa[r] = W3b + (size_t)rloc * D2 + c * 8;
    }
    const unsigned short* pb[2];
    #pragma unroll
    for (int r = 0; r < 2; r++) {
        int ii = w * 2 + r;
        int rloc = ii * 16 + rsub;               // 0..127
        int c = swz_src(rloc, l);
        pb[r] = Bsrc + (size_t)(n0 + rloc) * D2 + c * 8;
    }
    int aoff[4], boff[8];
    #pragma unroll
    for (int mt = 0; mt < 4; mt++) aoff[mt] = swz_frag(wm + mt * 16 + l16, quad);
    #pragma unroll
    for (int nt = 0; nt < 8; nt++) boff[nt] = swz_frag(nt * 16 + l16, quad);

    f32x4 acc[4][8];
    #pragma unroll
    for (int i = 0; i < 4; i++)
        #pragma unroll
        for (int j = 0; j < 8; j++) acc[i][j] = (f32x4)0.f;

    for (int kk = 0; kk < D2; kk += 32) {
        #pragma unroll
        for (int r = 0; r < 4; r++)
            gld16(pa[r] + kk, As + (w * 4 + r) * 512);
        #pragma unroll
        for (int r = 0; r < 2; r++)
            gld16(pb[r] + kk, Bs + (w * 2 + r) * 512);
        __syncthreads();
        short8 a[4], bf[8];
        #pragma unroll
        for (int mt = 0; mt < 4; mt++)
            a[mt] = *(const short8*)(As + aoff[mt]);
        #pragma unroll
        for (int nt = 0; nt < 8; nt++)
            bf[nt] = *(const short8*)(Bs + boff[nt]);
        #pragma unroll
        for (int mt = 0; mt < 4; mt++)
            #pragma unroll
            for (int nt = 0; nt < 8; nt++)
                acc[mt][nt] = __builtin_amdgcn_mfma_f32_16x16x32_bf16(
                    a[mt], bf[nt], acc[mt][nt], 0, 0, 0);
        __syncthreads();
    }

    #pragma unroll
    for (int mt = 0; mt < 4; mt++)
        #pragma unroll
        for (int r = 0; r < 4; r++) {
            float s = 0.f;
            #pragma unroll
            for (int nt = 0; nt < 8; nt++) { float v = acc[mt][nt][r]; s += v * v; }
            s += __shfl_down(s, 8, 64);
            s += __shfl_down(s, 4, 64);
            s += __shfl_down(s, 2, 64);
            s += __shfl_down(s, 1, 64);
            if (l16 == 0)
                atomicAdd(&norm3[(size_t)b * D3 + wm + mt * 16 + quad * 4 + r], s);
        }
}

// ---- dist2 + dist3 ---------------------------------------------------------
__global__ __launch_bounds__(256) void k_dist23(
    const float* __restrict__ z2, const float* __restrict__ z3,
    const float* __restrict__ norm2, const float* __restrict__ norm3,
    float* __restrict__ dists) {
    int i = blockIdx.x * 256 + threadIdx.x;
    if (i < B * D2) {
        int b = i >> 9, o = i & (D2 - 1);
        dists[(size_t)b * NDIST + D1 + o] = fabsf(z2[i]) / sqrtf(norm2[i]);
    } else {
        int j = i - B * D2;
        int b = j >> 8, p = j & (D3 - 1);
        dists[(size_t)b * NDIST + D1 + D2 + p] = fabsf(z3[j]) / sqrtf(norm3[j]);
    }
}

// ---- per-batch k-smallest sum ----------------------------------------------
__global__ __launch_bounds__(256) void k_topk(const float* __restrict__ dists,
                                              const int* __restrict__ kp,
                                              float* __restrict__ partial) {
    __shared__ unsigned long long wmin[4];
    int b = blockIdx.x, t = threadIdx.x;
    float lv[7];
    #pragma unroll
    for (int j = 0; j < 7; j++) lv[j] = dists[(size_t)b * NDIST + t + 256 * j];
    int k = *kp;
    if (k > NDIST) k = NDIST;
    float sum = 0.f;
    for (int it = 0; it < k; it++) {
        float mv = lv[0]; int mj = 0;
        #pragma unroll
        for (int j = 1; j < 7; j++)
            if (lv[j] < mv) { mv = lv[j]; mj = j; }
        unsigned long long key =
            ((unsigned long long)__float_as_uint(mv) << 32) | (unsigned)(t * 8 + mj);
        #pragma unroll
        for (int off = 32; off > 0; off >>= 1) {
            unsigned long long o = __shfl_down(key, off, 64);
            if (o < key) key = o;
        }
        if ((t & 63) == 0) wmin[t >> 6] = key;
        __syncthreads();
        unsigned long long k0 = wmin[0];
        #pragma unroll
        for (int ww = 1; ww < 4; ww++) if (wmin[ww] < k0) k0 = wmin[ww];
        sum += __uint_as_float((unsigned)(k0 >> 32));
        int wt = (int)((k0 & 0xFFFu) >> 3), wj = (int)(k0 & 7u);
        if (t == wt) lv[wj] = FLT_MAX;
        __syncthreads();
    }
    if (t == 0) partial[b] = sum;
}

// ---- final reduce ----------------------------------------------------------
__global__ __launch_bounds__(256) void k_final(const float* __restrict__ partial,
                                               float* __restrict__ out) {
    __shared__ float s[4];
    int t = threadIdx.x;
    float v = (t < B) ? partial[t] : 0.f;
    v = waveReduceSum(v);
    if ((t & 63) == 0) s[t >> 6] = v;
    __syncthreads();
    if (t == 0) out[0] = s[0] + s[1] + s[2] + s[3];
}

extern "C" void kernel_launch(void* const* d_in, const int* in_sizes, int n_in,
                              void* d_out, int out_size, void* d_ws, size_t ws_size,
                              hipStream_t stream) {
    const float* x  = (const float*)d_in[0];
    const float* W1 = (const float*)d_in[1];
    const float* b1 = (const float*)d_in[2];
    const float* W2 = (const float*)d_in[3];
    const float* b2 = (const float*)d_in[4];
    const float* W3 = (const float*)d_in[5];
    const float* b3 = (const float*)d_in[6];
    const int*   kp = (const int*)d_in[7];
    float* outp = (float*)d_out;

    float* fp = (float*)d_ws;
    float* rn1     = fp;                          fp += D1;
    float* z2      = fp;                          fp += (size_t)B * D2;
    float* z3      = fp;                          fp += (size_t)B * D3;
    float* dists   = fp;                          fp += (size_t)B * NDIST;
    float* partial = fp;                          fp += 256;
    float* norm2   = fp;                          fp += (size_t)B * D2;
    float* norm3   = fp;                          fp += (size_t)B * D3;
    unsigned short* up = (unsigned short*)fp;
    unsigned short* W1T   = up;  up += (size_t)D * D1;
    unsigned short* W2hi  = up;  up += (size_t)D2 * D1;
    unsigned short* W2lo  = up;  up += (size_t)D2 * D1;
    unsigned short* W3hi  = up;  up += (size_t)D3 * D2;
    unsigned short* W3lo  = up;  up += (size_t)D3 * D2;
    unsigned short* xhi   = up;  up += (size_t)B * D;
    unsigned short* xlo   = up;  up += (size_t)B * D;
    unsigned short* W1hi  = up;  up += (size_t)D1 * D;
    unsigned short* W1lo  = up;  up += (size_t)D1 * D;
    unsigned short* h1hi  = up;  up += (size_t)B * D1;
    unsigned short* h1lo  = up;  up += (size_t)B * D1;
    unsigned short* h2hi  = up;  up += (size_t)B * D2;
    unsigned short* h2lo  = up;  up += (size_t)B * D2;
    unsigned short* m1and = up;  up += (size_t)B * D1;
    unsigned short* V2mT  = up;

    size_t base_bytes = (size_t)((char*)V2mT - (char*)d_ws);
    int CH = 8;
    const int cands[6] = {256, 128, 64, 32, 16, 8};
    for (int c = 0; c < 6; c++) {
        size_t need = base_bytes + (size_t)cands[c] * D * D2 * sizeof(unsigned short);
        if (need <= ws_size) { CH = cands[c]; break; }
    }

    k_zero<<<(B * D2 + B * D3) / 256, 256, 0, stream>>>(norm2, B * D2 + B * D3);
    k_cvtall<<<960, 256, 0, stream>>>(x, W1, W2, W3, xhi, xlo, W1hi, W1lo,
                                      W2hi, W2lo, W3hi, W3lo);
    k_w1t<<<dim3(D1 / 32, D / 32), 256, 0, stream>>>(W1, W1T);
    k_rn1<<<D1 / 4, 256, 0, stream>>>(W1, rn1);

    k_l1<<<dim3(B / 64, D1 / 64), 256, 0, stream>>>(xhi, xlo, W1hi, W1lo, b1, rn1,
                                                    dists, m1and, h1hi, h1lo);
    k_l2<<<dim3(B / 64, D2 / 64), 256, 0, stream>>>(h1hi, h1lo, W2hi, W2lo, b2,
                                                    z2, h2hi, h2lo);
    k_l3<<<dim3(B / 64, D3 / 64), 256, 0, stream>>>(h2hi, h2lo, W3hi, W3lo, b3, z3);

    for (int b0 = 0; b0 < B; b0 += CH) {
        k_gemm1<<<dim3(D / 128, D2 / 128, CH), 256, 0, stream>>>(
            W1T, W2hi, m1and, z2, V2mT, norm2, b0);
        k_gemm2<<<dim3(D / 128, CH), 256, 0, stream>>>(W3hi, V2mT, norm3, b0);
    }

    k_dist23<<<(B * D2 + B * D3) / 256, 256, 0, stream>>>(z2, z3, norm2, norm3, dists);
    k_topk<<<B, 256, 0, stream>>>(dists, kp, partial);
    k_final<<<1, 256, 0, stream>>>(partial, outp);
}

// Round 5
// 226.977 us; speedup vs baseline: 12.6068x; 1.2424x over previous
//
#include <hip/hip_runtime.h>
#include <math.h>
#include <float.h>

#define B   256
#define D   256
#define D1  1024
#define D2  512
#define D3  256
#define NDIST (D1 + D2 + D3)   // 1792

typedef __attribute__((ext_vector_type(8))) short short8;
typedef __attribute__((ext_vector_type(4))) float f32x4;
typedef __attribute__((ext_vector_type(4))) int   i32x4;

__device__ __forceinline__ float waveReduceSum(float v) {
    #pragma unroll
    for (int off = 32; off > 0; off >>= 1)
        v += __shfl_down(v, off, 64);
    return v;
}
__device__ __forceinline__ float waveReduceMax(float v) {
    #pragma unroll
    for (int off = 32; off > 0; off >>= 1)
        v = fmaxf(v, __shfl_down(v, off, 64));
    return v;
}

__device__ __forceinline__ unsigned short f2bf(float f) {
    unsigned int u = __float_as_uint(f);
    u = (u + 0x7FFFu + ((u >> 16) & 1u)) >> 16;   // RNE
    return (unsigned short)u;
}
__device__ __forceinline__ float bf2f(unsigned short h) {
    return __uint_as_float(((unsigned int)h) << 16);
}
__device__ __forceinline__ void gld16(const void* g, void* l) {
    __builtin_amdgcn_global_load_lds(
        (const __attribute__((address_space(1))) unsigned int*)g,
        (__attribute__((address_space(3))) unsigned int*)l, 16, 0, 0);
}

// bf16 tile swizzle helpers (R4-proven: 0 bank conflicts)
__device__ __forceinline__ int swz_src(int row, int lane) {
    return ((lane & 3) + ((row >> 1) & 3)) & 3;
}
__device__ __forceinline__ int swz_frag(int row, int quad) {
    return row * 32 + (((quad - ((row >> 1) & 3)) & 3) * 8);
}
__device__ __forceinline__ short8 as_s8(uint4 v) {
    union { uint4 u; short8 s; } c; c.u = v; return c.s;
}

// ---- fused zero(norm2,norm3) + hi/lo split of x,W1,W2,W3 -------------------
__global__ __launch_bounds__(256) void k_prep(
    const float* __restrict__ x,  const float* __restrict__ W1,
    const float* __restrict__ W2, const float* __restrict__ W3,
    float* __restrict__ norms,                 // norm2||norm3, 196608 floats
    unsigned short* __restrict__ xhi,  unsigned short* __restrict__ xlo,
    unsigned short* __restrict__ W1hi, unsigned short* __restrict__ W1lo,
    unsigned short* __restrict__ W2hi, unsigned short* __restrict__ W2lo,
    unsigned short* __restrict__ W3hi, unsigned short* __restrict__ W3lo) {
    int blk = blockIdx.x;
    if (blk < 768) {
        norms[blk * 256 + threadIdx.x] = 0.f;
        return;
    }
    int i4 = ((blk - 768) * 256 + threadIdx.x) * 4;
    const float* src; unsigned short *hi, *lo; int off;
    if (i4 < 65536)       { src = x;  hi = xhi;  lo = xlo;  off = i4; }
    else if (i4 < 327680) { src = W1; hi = W1hi; lo = W1lo; off = i4 - 65536; }
    else if (i4 < 851968) { src = W2; hi = W2hi; lo = W2lo; off = i4 - 327680; }
    else                  { src = W3; hi = W3hi; lo = W3lo; off = i4 - 851968; }
    float4 v = *(const float4*)(src + off);
    ushort4 h, l;
    h.x = f2bf(v.x); l.x = f2bf(v.x - bf2f(h.x));
    h.y = f2bf(v.y); l.y = f2bf(v.y - bf2f(h.y));
    h.z = f2bf(v.z); l.z = f2bf(v.z - bf2f(h.z));
    h.w = f2bf(v.w); l.w = f2bf(v.w - bf2f(h.w));
    *(ushort4*)(hi + off) = h;
    *(ushort4*)(lo + off) = l;
}

// ---- W1 [1024][256] -> W1Ti8 [256(d)][1024(i)] per-d-row int8 + scales -----
__global__ __launch_bounds__(256) void k_w1tq(const float* __restrict__ W1,
                                              signed char* __restrict__ W1Ti8,
                                              float* __restrict__ saq) {
    int ty = threadIdx.x >> 5, tx = threadIdx.x & 31;
    int d = blockIdx.x * 8 + ty;
    float m = 0.f;
    for (int i = tx; i < D1; i += 32) m = fmaxf(m, fabsf(W1[(size_t)i * D + d]));
    #pragma unroll
    for (int off = 16; off > 0; off >>= 1) m = fmaxf(m, __shfl_down(m, off, 32));
    m = __shfl(m, 0, 32);
    m = fmaxf(m, 1e-20f);
    if (tx == 0) saq[d] = m / 127.f;
    float inv = 127.f / m;
    for (int i = tx; i < D1; i += 32) {
        int q = __float2int_rn(W1[(size_t)i * D + d] * inv);
        W1Ti8[(size_t)d * D1 + i] = (signed char)q;
    }
}

// ---- W2 [512][1024] -> int8 rows + scales ----------------------------------
__global__ __launch_bounds__(256) void k_w2q(const float* __restrict__ W2,
                                             signed char* __restrict__ W2i8,
                                             float* __restrict__ sbq) {
    int o = blockIdx.x * 4 + (threadIdx.x >> 6);
    int l = threadIdx.x & 63;
    const float* row = W2 + (size_t)o * D1;
    float m = 0.f;
    for (int t = l; t < D1; t += 64) m = fmaxf(m, fabsf(row[t]));
    m = waveReduceMax(m);
    m = __shfl(m, 0, 64);
    m = fmaxf(m, 1e-20f);
    if (l == 0) sbq[o] = m / 127.f;
    float inv = 127.f / m;
    for (int t = l; t < D1; t += 64) {
        int q = __float2int_rn(row[t] * inv);
        W2i8[(size_t)o * D1 + t] = (signed char)q;
    }
}

// ---- W1 row norms ----------------------------------------------------------
__global__ __launch_bounds__(256) void k_rn1(const float* __restrict__ W1,
                                             float* __restrict__ rn1) {
    int gw = (blockIdx.x * blockDim.x + threadIdx.x) >> 6;
    int lane = threadIdx.x & 63;
    if (gw >= D1) return;
    const float* row = W1 + (size_t)gw * D;
    float s = 0.f;
    for (int t = lane; t < D; t += 64) { float v = row[t]; s += v * v; }
    s = waveReduceSum(s);
    if (lane == 0) rn1[gw] = sqrtf(s);
}

// ---- compensated bf16 MFMA mainloop for a 64x64 tile, C = A @ B^T ----------
template <int KD>
__device__ __forceinline__ void mfma3_64(
    const unsigned short* __restrict__ Ahi, const unsigned short* __restrict__ Alo,
    const unsigned short* __restrict__ Bhi, const unsigned short* __restrict__ Blo,
    int m0, int n0, unsigned short* sm, f32x4 acc[2][2]) {
    int tid = threadIdx.x;
    int l = tid & 63, w = tid >> 6;
    int rsub = l >> 2;
    int quad = l >> 4, l16 = l & 15;
    int wm = (w >> 1) * 32, wn = (w & 1) * 32;
    unsigned short* sAh = sm;
    unsigned short* sAl = sm + 2048;
    unsigned short* sBh = sm + 4096;
    unsigned short* sBl = sm + 6144;
    ptrdiff_t dA = Alo - Ahi, dB = Blo - Bhi;
    int rloc = w * 16 + rsub;
    int c = swz_src(rloc, l);
    const unsigned short* pa = Ahi + (size_t)(m0 + rloc) * KD + c * 8;
    const unsigned short* pb = Bhi + (size_t)(n0 + rloc) * KD + c * 8;
    int aoff[2], boff[2];
    #pragma unroll
    for (int mt = 0; mt < 2; mt++) aoff[mt] = swz_frag(wm + mt * 16 + l16, quad);
    #pragma unroll
    for (int nt = 0; nt < 2; nt++) boff[nt] = swz_frag(wn + nt * 16 + l16, quad);
    for (int kk = 0; kk < KD; kk += 32) {
        gld16(pa + kk,      sAh + w * 512);
        gld16(pa + dA + kk, sAl + w * 512);
        gld16(pb + kk,      sBh + w * 512);
        gld16(pb + dB + kk, sBl + w * 512);
        __syncthreads();
        short8 ah[2], al[2], bh[2], bl[2];
        #pragma unroll
        for (int mt = 0; mt < 2; mt++) {
            ah[mt] = *(const short8*)(sAh + aoff[mt]);
            al[mt] = *(const short8*)(sAl + aoff[mt]);
        }
        #pragma unroll
        for (int nt = 0; nt < 2; nt++) {
            bh[nt] = *(const short8*)(sBh + boff[nt]);
            bl[nt] = *(const short8*)(sBl + boff[nt]);
        }
        #pragma unroll
        for (int mt = 0; mt < 2; mt++)
            #pragma unroll
            for (int nt = 0; nt < 2; nt++) {
                acc[mt][nt] = __builtin_amdgcn_mfma_f32_16x16x32_bf16(ah[mt], bh[nt], acc[mt][nt], 0, 0, 0);
                acc[mt][nt] = __builtin_amdgcn_mfma_f32_16x16x32_bf16(ah[mt], bl[nt], acc[mt][nt], 0, 0, 0);
                acc[mt][nt] = __builtin_amdgcn_mfma_f32_16x16x32_bf16(al[mt], bh[nt], acc[mt][nt], 0, 0, 0);
            }
        __syncthreads();
    }
}

// ---- layer 1: z1 -> dist1 (stride D1), m1q bytes, h1 hi/lo -----------------
__global__ __launch_bounds__(256) void k_l1(
    const unsigned short* __restrict__ xhi,  const unsigned short* __restrict__ xlo,
    const unsigned short* __restrict__ W1hi, const unsigned short* __restrict__ W1lo,
    const float* __restrict__ b1, const float* __restrict__ rn1,
    float* __restrict__ dists, unsigned char* __restrict__ m1q,
    unsigned short* __restrict__ h1hi, unsigned short* __restrict__ h1lo) {
    __shared__ __align__(16) unsigned short sm[8192];
    int m0 = blockIdx.x * 64, n0 = blockIdx.y * 64;
    f32x4 acc[2][2] = {};
    mfma3_64<D>(xhi, xlo, W1hi, W1lo, m0, n0, sm, acc);
    int l = threadIdx.x & 63, w = threadIdx.x >> 6;
    int quad = l >> 4, l16 = l & 15;
    int wm = (w >> 1) * 32, wn = (w & 1) * 32;
    #pragma unroll
    for (int mt = 0; mt < 2; mt++)
        #pragma unroll
        for (int nt = 0; nt < 2; nt++) {
            int n = n0 + wn + nt * 16 + l16;
            float bv = b1[n], rv = rn1[n];
            #pragma unroll
            for (int r = 0; r < 4; r++) {
                int m = m0 + wm + mt * 16 + quad * 4 + r;
                float z = acc[mt][nt][r] + bv;
                size_t idx = (size_t)m * D1 + n;
                dists[idx] = fabsf(z) / rv;
                m1q[idx] = (z > 0.f) ? 0xFFu : 0u;
                float h = z > 0.f ? z : 0.f;
                unsigned short hh = f2bf(h);
                h1hi[idx] = hh;
                h1lo[idx] = f2bf(h - bf2f(hh));
            }
        }
}

// ---- layer 2 ---------------------------------------------------------------
__global__ __launch_bounds__(256) void k_l2(
    const unsigned short* __restrict__ h1hi, const unsigned short* __restrict__ h1lo,
    const unsigned short* __restrict__ W2hi, const unsigned short* __restrict__ W2lo,
    const float* __restrict__ b2, float* __restrict__ z2,
    unsigned short* __restrict__ h2hi, unsigned short* __restrict__ h2lo) {
    __shared__ __align__(16) unsigned short sm[8192];
    int m0 = blockIdx.x * 64, n0 = blockIdx.y * 64;
    f32x4 acc[2][2] = {};
    mfma3_64<D1>(h1hi, h1lo, W2hi, W2lo, m0, n0, sm, acc);
    int l = threadIdx.x & 63, w = threadIdx.x >> 6;
    int quad = l >> 4, l16 = l & 15;
    int wm = (w >> 1) * 32, wn = (w & 1) * 32;
    #pragma unroll
    for (int mt = 0; mt < 2; mt++)
        #pragma unroll
        for (int nt = 0; nt < 2; nt++) {
            int n = n0 + wn + nt * 16 + l16;
            float bv = b2[n];
            #pragma unroll
            for (int r = 0; r < 4; r++) {
                int m = m0 + wm + mt * 16 + quad * 4 + r;
                float z = acc[mt][nt][r] + bv;
                size_t idx = (size_t)m * D2 + n;
                z2[idx] = z;
                float h = z > 0.f ? z : 0.f;
                unsigned short hh = f2bf(h);
                h2hi[idx] = hh;
                h2lo[idx] = f2bf(h - bf2f(hh));
            }
        }
}

// ---- layer 3 ---------------------------------------------------------------
__global__ __launch_bounds__(256) void k_l3(
    const unsigned short* __restrict__ h2hi, const unsigned short* __restrict__ h2lo,
    const unsigned short* __restrict__ W3hi, const unsigned short* __restrict__ W3lo,
    const float* __restrict__ b3, float* __restrict__ z3) {
    __shared__ __align__(16) unsigned short sm[8192];
    int m0 = blockIdx.x * 64, n0 = blockIdx.y * 64;
    f32x4 acc[2][2] = {};
    mfma3_64<D2>(h2hi, h2lo, W3hi, W3lo, m0, n0, sm, acc);
    int l = threadIdx.x & 63, w = threadIdx.x >> 6;
    int quad = l >> 4, l16 = l & 15;
    int wm = (w >> 1) * 32, wn = (w & 1) * 32;
    #pragma unroll
    for (int mt = 0; mt < 2; mt++)
        #pragma unroll
        for (int nt = 0; nt < 2; nt++) {
            int n = n0 + wn + nt * 16 + l16;
            float bv = b3[n];
            #pragma unroll
            for (int r = 0; r < 4; r++) {
                int m = m0 + wm + mt * 16 + quad * 4 + r;
                z3[(size_t)m * D3 + n] = acc[mt][nt][r] + bv;
            }
        }
}

// ---- GEMM1 (int8): V2T[d][o] = sa[d]*sb[o] * sum_i (m1&qW1T)[d][i]*qW2[o][i]
// 128x128 tile, BK=64 bytes, 16 iters; mask as byte-AND on A fragments.
__global__ __launch_bounds__(256) void k_gemm1(
    const signed char* __restrict__ W1Ti8,   // [256][1024]
    const signed char* __restrict__ W2i8,    // [512][1024]
    const unsigned char* __restrict__ m1q,   // [B][1024]
    const float* __restrict__ saq,           // [256]
    const float* __restrict__ sbq,           // [512]
    const float* __restrict__ z2,            // [B][512]
    unsigned short* __restrict__ V2mT,       // [CH][256][512]
    float* __restrict__ norm2,               // [B][512]
    int b0) {
    __shared__ __align__(16) signed char As[8192];   // 128 rows x 64B
    __shared__ __align__(16) signed char Bs[8192];
    int m0 = blockIdx.x * 128;        // d
    int o0 = blockIdx.y * 128;        // o
    int bc = blockIdx.z;
    int b = b0 + bc;
    int tid = threadIdx.x;
    int l = tid & 63, w = tid >> 6;
    int rsub = l >> 2, cq = l & 3;
    int quad = l >> 4, l16 = l & 15;
    int wm = (w >> 1) * 64, wn = (w & 1) * 64;
    const unsigned char* mrow = m1q + (size_t)b * D1;

    const signed char* pa[2];
    const signed char* pb[2];
    #pragma unroll
    for (int r = 0; r < 2; r++) {
        int rloc = w * 32 + r * 16 + rsub;
        int c = (cq + ((rsub >> 1) & 3)) & 3;   // slot cq holds global chunk c
        pa[r] = W1Ti8 + (size_t)(m0 + rloc) * D1 + c * 16;
        pb[r] = W2i8 + (size_t)(o0 + rloc) * D1 + c * 16;
    }
    int hq = (l16 >> 1) & 3;
    int slot = ((quad - hq) & 3) * 16;
    int aoff[4], boff[4];
    #pragma unroll
    for (int mt = 0; mt < 4; mt++) aoff[mt] = (wm + mt * 16 + l16) * 64 + slot;
    #pragma unroll
    for (int nt = 0; nt < 4; nt++) boff[nt] = (wn + nt * 16 + l16) * 64 + slot;

    i32x4 acc[4][4];
    #pragma unroll
    for (int i = 0; i < 4; i++)
        #pragma unroll
        for (int j = 0; j < 4; j++) acc[i][j] = (i32x4)0;

    for (int kk = 0; kk < D1; kk += 64) {
        #pragma unroll
        for (int r = 0; r < 2; r++) {
            gld16(pa[r] + kk, As + w * 2048 + r * 1024);
            gld16(pb[r] + kk, Bs + w * 2048 + r * 1024);
        }
        i32x4 mv = *(const i32x4*)(mrow + kk + quad * 16);
        __syncthreads();
        i32x4 a[4], bq[4];
        #pragma unroll
        for (int mt = 0; mt < 4; mt++)
            a[mt] = (*(const i32x4*)(As + aoff[mt])) & mv;
        #pragma unroll
        for (int nt = 0; nt < 4; nt++)
            bq[nt] = *(const i32x4*)(Bs + boff[nt]);
        #pragma unroll
        for (int mt = 0; mt < 4; mt++)
            #pragma unroll
            for (int nt = 0; nt < 4; nt++)
                acc[mt][nt] = __builtin_amdgcn_mfma_i32_16x16x64_i8(
                    a[mt], bq[nt], acc[mt][nt], 0, 0, 0);
        __syncthreads();
    }

    // dequant scales
    float sad[4][4];
    #pragma unroll
    for (int mt = 0; mt < 4; mt++)
        #pragma unroll
        for (int r = 0; r < 4; r++)
            sad[mt][r] = saq[m0 + wm + mt * 16 + quad * 4 + r];
    float sbv[4], z2v[4];
    #pragma unroll
    for (int nt = 0; nt < 4; nt++) {
        int o = o0 + wn + nt * 16 + l16;
        sbv[nt] = sbq[o];
        z2v[nt] = z2[(size_t)b * D2 + o];
    }
    f32x4 vacc[4][4];
    #pragma unroll
    for (int mt = 0; mt < 4; mt++)
        #pragma unroll
        for (int nt = 0; nt < 4; nt++)
            #pragma unroll
            for (int r = 0; r < 4; r++)
                vacc[mt][nt][r] = (float)acc[mt][nt][r] * sad[mt][r] * sbv[nt];

    // norm2 (pre-m2 mask)
    #pragma unroll
    for (int nt = 0; nt < 4; nt++) {
        float s = 0.f;
        #pragma unroll
        for (int mt = 0; mt < 4; mt++)
            #pragma unroll
            for (int r = 0; r < 4; r++) { float v = vacc[mt][nt][r]; s += v * v; }
        s += __shfl_down(s, 32, 64);
        s += __shfl_down(s, 16, 64);
        if (l < 16)
            atomicAdd(&norm2[(size_t)b * D2 + o0 + wn + nt * 16 + l], s);
    }

    // m2-masked bf16 store of V2mT
    unsigned short* outb = V2mT + (size_t)bc * (D * D2);
    #pragma unroll
    for (int mt = 0; mt < 4; mt++) {
        int dbase = m0 + wm + mt * 16 + quad * 4;
        #pragma unroll
        for (int r = 0; r < 4; r++)
            #pragma unroll
            for (int nt = 0; nt < 4; nt++) {
                int o = o0 + wn + nt * 16 + l16;
                float v = (z2v[nt] > 0.f) ? vacc[mt][nt][r] : 0.f;
                outb[(size_t)(dbase + r) * D2 + o] = f2bf(v);
            }
    }
}

// ---- GEMM2 (bf16): norm3[b][p] += sum_d (sum_o W3[p][o] * V2mT[d][o])^2 ----
__global__ __launch_bounds__(256, 1) void k_gemm2(
    const unsigned short* __restrict__ W3b,    // [256][512] (= W3hi)
    const unsigned short* __restrict__ V2mT,   // [CH][256][512]
    float* __restrict__ norm3,                 // [B][256]
    int b0) {
    __shared__ __align__(16) unsigned short As[8192];   // 256x32
    __shared__ __align__(16) unsigned short Bs[4096];   // 128x32
    int n0 = blockIdx.x * 128;   // d-tile
    int bc = blockIdx.y;
    int b = b0 + bc;
    int tid = threadIdx.x;
    int l = tid & 63, w = tid >> 6;
    int rsub = l >> 2;
    int quad = l >> 4, l16 = l & 15;
    int wm = w * 64;
    const unsigned short* Bsrc = V2mT + (size_t)bc * (D * D2);

    const unsigned short* pa[4];
    #pragma unroll
    for (int r = 0; r < 4; r++) {
        int rloc = (w * 4 + r) * 16 + rsub;
        int c = swz_src(rloc, l);
        pa[r] = W3b + (size_t)rloc * D2 + c * 8;
    }
    const unsigned short* pb[2];
    #pragma unroll
    for (int r = 0; r < 2; r++) {
        int rloc = (w * 2 + r) * 16 + rsub;
        int c = swz_src(rloc, l);
        pb[r] = Bsrc + (size_t)(n0 + rloc) * D2 + c * 8;
    }
    int aoff[4], boff[8];
    #pragma unroll
    for (int mt = 0; mt < 4; mt++) aoff[mt] = swz_frag(wm + mt * 16 + l16, quad);
    #pragma unroll
    for (int nt = 0; nt < 8; nt++) boff[nt] = swz_frag(nt * 16 + l16, quad);

    f32x4 acc[4][8];
    #pragma unroll
    for (int i = 0; i < 4; i++)
        #pragma unroll
        for (int j = 0; j < 8; j++) acc[i][j] = (f32x4)0.f;

    for (int kk = 0; kk < D2; kk += 32) {
        #pragma unroll
        for (int r = 0; r < 4; r++)
            gld16(pa[r] + kk, As + (w * 4 + r) * 512);
        #pragma unroll
        for (int r = 0; r < 2; r++)
            gld16(pb[r] + kk, Bs + (w * 2 + r) * 512);
        __syncthreads();
        short8 a[4], bf[8];
        #pragma unroll
        for (int mt = 0; mt < 4; mt++)
            a[mt] = *(const short8*)(As + aoff[mt]);
        #pragma unroll
        for (int nt = 0; nt < 8; nt++)
            bf[nt] = *(const short8*)(Bs + boff[nt]);
        #pragma unroll
        for (int mt = 0; mt < 4; mt++)
            #pragma unroll
            for (int nt = 0; nt < 8; nt++)
                acc[mt][nt] = __builtin_amdgcn_mfma_f32_16x16x32_bf16(
                    a[mt], bf[nt], acc[mt][nt], 0, 0, 0);
        __syncthreads();
    }

    #pragma unroll
    for (int mt = 0; mt < 4; mt++)
        #pragma unroll
        for (int r = 0; r < 4; r++) {
            float s = 0.f;
            #pragma unroll
            for (int nt = 0; nt < 8; nt++) { float v = acc[mt][nt][r]; s += v * v; }
            s += __shfl_down(s, 8, 64);
            s += __shfl_down(s, 4, 64);
            s += __shfl_down(s, 2, 64);
            s += __shfl_down(s, 1, 64);
            if (l16 == 0)
                atomicAdd(&norm3[(size_t)b * D3 + wm + mt * 16 + quad * 4 + r], s);
        }
}

// ---- per-batch k-smallest sum; dist2/dist3 computed inline on load ---------
__global__ __launch_bounds__(256) void k_topk(
    const float* __restrict__ dists,    // [B][D1] dist1 only
    const float* __restrict__ z2, const float* __restrict__ norm2,
    const float* __restrict__ z3, const float* __restrict__ norm3,
    const int* __restrict__ kp, float* __restrict__ partial) {
    __shared__ unsigned long long wmin[4];
    int b = blockIdx.x, t = threadIdx.x;
    float lv[7];
    #pragma unroll
    for (int j = 0; j < 4; j++) lv[j] = dists[(size_t)b * D1 + t + 256 * j];
    #pragma unroll
    for (int j = 4; j < 6; j++) {
        int o = t + 256 * j - 1024;
        lv[j] = fabsf(z2[(size_t)b * D2 + o]) / sqrtf(norm2[(size_t)b * D2 + o]);
    }
    {
        int p = t;
        lv[6] = fabsf(z3[(size_t)b * D3 + p]) / sqrtf(norm3[(size_t)b * D3 + p]);
    }
    int k = *kp;
    if (k > NDIST) k = NDIST;
    float sum = 0.f;
    for (int it = 0; it < k; it++) {
        float mv = lv[0]; int mj = 0;
        #pragma unroll
        for (int j = 1; j < 7; j++)
            if (lv[j] < mv) { mv = lv[j]; mj = j; }
        unsigned long long key =
            ((unsigned long long)__float_as_uint(mv) << 32) | (unsigned)(t * 8 + mj);
        #pragma unroll
        for (int off = 32; off > 0; off >>= 1) {
            unsigned long long o = __shfl_down(key, off, 64);
            if (o < key) key = o;
        }
        if ((t & 63) == 0) wmin[t >> 6] = key;
        __syncthreads();
        unsigned long long k0 = wmin[0];
        #pragma unroll
        for (int ww = 1; ww < 4; ww++) if (wmin[ww] < k0) k0 = wmin[ww];
        sum += __uint_as_float((unsigned)(k0 >> 32));
        int wt = (int)((k0 & 0xFFFu) >> 3), wj = (int)(k0 & 7u);
        if (t == wt) lv[wj] = FLT_MAX;
        __syncthreads();
    }
    if (t == 0) partial[b] = sum;
}

// ---- final reduce ----------------------------------------------------------
__global__ __launch_bounds__(256) void k_final(const float* __restrict__ partial,
                                               float* __restrict__ out) {
    __shared__ float s[4];
    int t = threadIdx.x;
    float v = (t < B) ? partial[t] : 0.f;
    v = waveReduceSum(v);
    if ((t & 63) == 0) s[t >> 6] = v;
    __syncthreads();
    if (t == 0) out[0] = s[0] + s[1] + s[2] + s[3];
}

extern "C" void kernel_launch(void* const* d_in, const int* in_sizes, int n_in,
                              void* d_out, int out_size, void* d_ws, size_t ws_size,
                              hipStream_t stream) {
    const float* x  = (const float*)d_in[0];
    const float* W1 = (const float*)d_in[1];
    const float* b1 = (const float*)d_in[2];
    const float* W2 = (const float*)d_in[3];
    const float* b2 = (const float*)d_in[4];
    const float* W3 = (const float*)d_in[5];
    const float* b3 = (const float*)d_in[6];
    const int*   kp = (const int*)d_in[7];
    float* outp = (float*)d_out;

    float* fp = (float*)d_ws;
    float* rn1     = fp;                          fp += D1;
    float* z2      = fp;                          fp += (size_t)B * D2;
    float* z3      = fp;                          fp += (size_t)B * D3;
    float* dists   = fp;                          fp += (size_t)B * D1;
    float* partial = fp;                          fp += 256;
    float* norm2   = fp;                          fp += (size_t)B * D2;   // norm2,norm3 contiguous
    float* norm3   = fp;                          fp += (size_t)B * D3;
    float* saq     = fp;                          fp += D;
    float* sbq     = fp;                          fp += D2;
    unsigned short* up = (unsigned short*)fp;
    unsigned short* W2hi  = up;  up += (size_t)D2 * D1;
    unsigned short* W2lo  = up;  up += (size_t)D2 * D1;
    unsigned short* W3hi  = up;  up += (size_t)D3 * D2;
    unsigned short* W3lo  = up;  up += (size_t)D3 * D2;
    unsigned short* xhi   = up;  up += (size_t)B * D;
    unsigned short* xlo   = up;  up += (size_t)B * D;
    unsigned short* W1hi  = up;  up += (size_t)D1 * D;
    unsigned short* W1lo  = up;  up += (size_t)D1 * D;
    unsigned short* h1hi  = up;  up += (size_t)B * D1;
    unsigned short* h1lo  = up;  up += (size_t)B * D1;
    unsigned short* h2hi  = up;  up += (size_t)B * D2;
    unsigned short* h2lo  = up;  up += (size_t)B * D2;
    signed char*    cp = (signed char*)up;
    signed char*    W1Ti8 = cp;  cp += (size_t)D * D1;
    signed char*    W2i8  = cp;  cp += (size_t)D2 * D1;
    unsigned char*  m1q   = (unsigned char*)cp;  cp += (size_t)B * D1;
    unsigned short* V2mT  = (unsigned short*)cp;

    size_t base_bytes = (size_t)((char*)V2mT - (char*)d_ws);
    int CH = 8;
    const int cands[6] = {256, 128, 64, 32, 16, 8};
    for (int c = 0; c < 6; c++) {
        size_t need = base_bytes + (size_t)cands[c] * D * D2 * sizeof(unsigned short);
        if (need <= ws_size) { CH = cands[c]; break; }
    }

    k_prep<<<1728, 256, 0, stream>>>(x, W1, W2, W3, norm2,
                                     xhi, xlo, W1hi, W1lo, W2hi, W2lo, W3hi, W3lo);
    k_w1tq<<<32, 256, 0, stream>>>(W1, W1Ti8, saq);
    k_w2q<<<128, 256, 0, stream>>>(W2, W2i8, sbq);
    k_rn1<<<D1 / 4, 256, 0, stream>>>(W1, rn1);

    k_l1<<<dim3(B / 64, D1 / 64), 256, 0, stream>>>(xhi, xlo, W1hi, W1lo, b1, rn1,
                                                    dists, m1q, h1hi, h1lo);
    k_l2<<<dim3(B / 64, D2 / 64), 256, 0, stream>>>(h1hi, h1lo, W2hi, W2lo, b2,
                                                    z2, h2hi, h2lo);
    k_l3<<<dim3(B / 64, D3 / 64), 256, 0, stream>>>(h2hi, h2lo, W3hi, W3lo, b3, z3);

    for (int b0 = 0; b0 < B; b0 += CH) {
        k_gemm1<<<dim3(D / 128, D2 / 128, CH), 256, 0, stream>>>(
            W1Ti8, W2i8, m1q, saq, sbq, z2, V2mT, norm2, b0);
        k_gemm2<<<dim3(D / 128, CH), 256, 0, stream>>>(W3hi, V2mT, norm3, b0);
    }

    k_topk<<<B, 256, 0, stream>>>(dists, z2, norm2, z3, norm3, kp, partial);
    k_final<<<1, 256, 0, stream>>>(partial, outp);
}

// Round 6
// 221.639 us; speedup vs baseline: 12.9105x; 1.0241x over previous
//
#include <hip/hip_runtime.h>
#include <math.h>
#include <float.h>

#define B   256
#define D   256
#define D1  1024
#define D2  512
#define D3  256
#define NDIST (D1 + D2 + D3)   // 1792
#define CQ  2.0f               // qV2 static scale multiplier (step = sa[d]*CQ)

typedef __attribute__((ext_vector_type(8))) short short8;
typedef __attribute__((ext_vector_type(4))) float f32x4;
typedef __attribute__((ext_vector_type(4))) int   i32x4;

__device__ __forceinline__ float waveReduceSum(float v) {
    #pragma unroll
    for (int off = 32; off > 0; off >>= 1)
        v += __shfl_down(v, off, 64);
    return v;
}
__device__ __forceinline__ float waveReduceMax(float v) {
    #pragma unroll
    for (int off = 32; off > 0; off >>= 1)
        v = fmaxf(v, __shfl_down(v, off, 64));
    return v;
}

__device__ __forceinline__ unsigned short f2bf(float f) {
    unsigned int u = __float_as_uint(f);
    u = (u + 0x7FFFu + ((u >> 16) & 1u)) >> 16;   // RNE
    return (unsigned short)u;
}
__device__ __forceinline__ float bf2f(unsigned short h) {
    return __uint_as_float(((unsigned int)h) << 16);
}
__device__ __forceinline__ void gld16(const void* g, void* l) {
    __builtin_amdgcn_global_load_lds(
        (const __attribute__((address_space(1))) unsigned int*)g,
        (__attribute__((address_space(3))) unsigned int*)l, 16, 0, 0);
}

// bf16 tile swizzle helpers (R4-proven: 0 bank conflicts)
__device__ __forceinline__ int swz_src(int row, int lane) {
    return ((lane & 3) + ((row >> 1) & 3)) & 3;
}
__device__ __forceinline__ int swz_frag(int row, int quad) {
    return row * 32 + (((quad - ((row >> 1) & 3)) & 3) * 8);
}

// ---- mega prep: zero norms+out, hi/lo splits, i8 quant of W1T/W2/W3, rn1 ---
__global__ __launch_bounds__(256) void k_prep(
    const float* __restrict__ x,  const float* __restrict__ W1,
    const float* __restrict__ W2, const float* __restrict__ W3,
    float* __restrict__ norms,                 // norm2||norm3, 196608 floats
    float* __restrict__ outp,
    unsigned short* __restrict__ xhi,  unsigned short* __restrict__ xlo,
    unsigned short* __restrict__ W1hi, unsigned short* __restrict__ W1lo,
    unsigned short* __restrict__ W2hi, unsigned short* __restrict__ W2lo,
    unsigned short* __restrict__ W3hi, unsigned short* __restrict__ W3lo,
    signed char* __restrict__ W1Ti8, float* __restrict__ saq,
    signed char* __restrict__ W2i8,  float* __restrict__ sbq,
    signed char* __restrict__ W3i8,  float* __restrict__ s3q,
    float* __restrict__ rn1) {
    int blk = blockIdx.x;
    int t = threadIdx.x;
    if (blk < 768) {                                   // zero norms (+ out)
        if (blk == 0 && t == 0) outp[0] = 0.f;
        norms[blk * 256 + t] = 0.f;
        return;
    }
    if (blk < 1728) {                                  // hi/lo splits
        int i4 = ((blk - 768) * 256 + t) * 4;
        const float* src; unsigned short *hi, *lo; int off;
        if (i4 < 65536)       { src = x;  hi = xhi;  lo = xlo;  off = i4; }
        else if (i4 < 327680) { src = W1; hi = W1hi; lo = W1lo; off = i4 - 65536; }
        else if (i4 < 851968) { src = W2; hi = W2hi; lo = W2lo; off = i4 - 327680; }
        else                  { src = W3; hi = W3hi; lo = W3lo; off = i4 - 851968; }
        float4 v = *(const float4*)(src + off);
        ushort4 h, l;
        h.x = f2bf(v.x); l.x = f2bf(v.x - bf2f(h.x));
        h.y = f2bf(v.y); l.y = f2bf(v.y - bf2f(h.y));
        h.z = f2bf(v.z); l.z = f2bf(v.z - bf2f(h.z));
        h.w = f2bf(v.w); l.w = f2bf(v.w - bf2f(h.w));
        *(ushort4*)(hi + off) = h;
        *(ushort4*)(lo + off) = l;
        return;
    }
    if (blk < 1760) {                                  // W1 col quant -> W1Ti8
        int ty = t >> 5, tx = t & 31;
        int d = (blk - 1728) * 8 + ty;
        float m = 0.f;
        for (int i = tx; i < D1; i += 32) m = fmaxf(m, fabsf(W1[(size_t)i * D + d]));
        #pragma unroll
        for (int off = 16; off > 0; off >>= 1) m = fmaxf(m, __shfl_down(m, off, 32));
        m = __shfl(m, 0, 32);
        m = fmaxf(m, 1e-20f);
        if (tx == 0) saq[d] = m / 127.f;
        float inv = 127.f / m;
        for (int i = tx; i < D1; i += 32) {
            int q = __float2int_rn(W1[(size_t)i * D + d] * inv);
            W1Ti8[(size_t)d * D1 + i] = (signed char)q;
        }
        return;
    }
    if (blk < 1888) {                                  // W2 row quant
        int o = (blk - 1760) * 4 + (t >> 6);
        int l = t & 63;
        const float* row = W2 + (size_t)o * D1;
        float m = 0.f;
        for (int tt = l; tt < D1; tt += 64) m = fmaxf(m, fabsf(row[tt]));
        m = waveReduceMax(m);
        m = __shfl(m, 0, 64);
        m = fmaxf(m, 1e-20f);
        if (l == 0) sbq[o] = m / 127.f;
        float inv = 127.f / m;
        for (int tt = l; tt < D1; tt += 64)
            W2i8[(size_t)o * D1 + tt] = (signed char)__float2int_rn(row[tt] * inv);
        return;
    }
    if (blk < 1952) {                                  // W3 row quant
        int p = (blk - 1888) * 4 + (t >> 6);
        int l = t & 63;
        const float* row = W3 + (size_t)p * D2;
        float m = 0.f;
        for (int tt = l; tt < D2; tt += 64) m = fmaxf(m, fabsf(row[tt]));
        m = waveReduceMax(m);
        m = __shfl(m, 0, 64);
        m = fmaxf(m, 1e-20f);
        if (l == 0) s3q[p] = m / 127.f;
        float inv = 127.f / m;
        for (int tt = l; tt < D2; tt += 64)
            W3i8[(size_t)p * D2 + tt] = (signed char)__float2int_rn(row[tt] * inv);
        return;
    }
    {                                                  // rn1 (W1 row norms)
        int gw = (blk - 1952) * 4 + (t >> 6);
        int lane = t & 63;
        const float* row = W1 + (size_t)gw * D;
        float s = 0.f;
        for (int tt = lane; tt < D; tt += 64) { float v = row[tt]; s += v * v; }
        s = waveReduceSum(s);
        if (lane == 0) rn1[gw] = sqrtf(s);
    }
}

// ---- compensated bf16 MFMA mainloop for a 64x64 tile, C = A @ B^T ----------
template <int KD>
__device__ __forceinline__ void mfma3_64(
    const unsigned short* __restrict__ Ahi, const unsigned short* __restrict__ Alo,
    const unsigned short* __restrict__ Bhi, const unsigned short* __restrict__ Blo,
    int m0, int n0, unsigned short* sm, f32x4 acc[2][2]) {
    int tid = threadIdx.x;
    int l = tid & 63, w = tid >> 6;
    int rsub = l >> 2;
    int quad = l >> 4, l16 = l & 15;
    int wm = (w >> 1) * 32, wn = (w & 1) * 32;
    unsigned short* sAh = sm;
    unsigned short* sAl = sm + 2048;
    unsigned short* sBh = sm + 4096;
    unsigned short* sBl = sm + 6144;
    ptrdiff_t dA = Alo - Ahi, dB = Blo - Bhi;
    int rloc = w * 16 + rsub;
    int c = swz_src(rloc, l);
    const unsigned short* pa = Ahi + (size_t)(m0 + rloc) * KD + c * 8;
    const unsigned short* pb = Bhi + (size_t)(n0 + rloc) * KD + c * 8;
    int aoff[2], boff[2];
    #pragma unroll
    for (int mt = 0; mt < 2; mt++) aoff[mt] = swz_frag(wm + mt * 16 + l16, quad);
    #pragma unroll
    for (int nt = 0; nt < 2; nt++) boff[nt] = swz_frag(wn + nt * 16 + l16, quad);
    for (int kk = 0; kk < KD; kk += 32) {
        gld16(pa + kk,      sAh + w * 512);
        gld16(pa + dA + kk, sAl + w * 512);
        gld16(pb + kk,      sBh + w * 512);
        gld16(pb + dB + kk, sBl + w * 512);
        __syncthreads();
        short8 ah[2], al[2], bh[2], bl[2];
        #pragma unroll
        for (int mt = 0; mt < 2; mt++) {
            ah[mt] = *(const short8*)(sAh + aoff[mt]);
            al[mt] = *(const short8*)(sAl + aoff[mt]);
        }
        #pragma unroll
        for (int nt = 0; nt < 2; nt++) {
            bh[nt] = *(const short8*)(sBh + boff[nt]);
            bl[nt] = *(const short8*)(sBl + boff[nt]);
        }
        #pragma unroll
        for (int mt = 0; mt < 2; mt++)
            #pragma unroll
            for (int nt = 0; nt < 2; nt++) {
                acc[mt][nt] = __builtin_amdgcn_mfma_f32_16x16x32_bf16(ah[mt], bh[nt], acc[mt][nt], 0, 0, 0);
                acc[mt][nt] = __builtin_amdgcn_mfma_f32_16x16x32_bf16(ah[mt], bl[nt], acc[mt][nt], 0, 0, 0);
                acc[mt][nt] = __builtin_amdgcn_mfma_f32_16x16x32_bf16(al[mt], bh[nt], acc[mt][nt], 0, 0, 0);
            }
        __syncthreads();
    }
}

// ---- layer 1: z1 -> dist1 (stride D1), m1q bytes, h1 hi/lo -----------------
__global__ __launch_bounds__(256) void k_l1(
    const unsigned short* __restrict__ xhi,  const unsigned short* __restrict__ xlo,
    const unsigned short* __restrict__ W1hi, const unsigned short* __restrict__ W1lo,
    const float* __restrict__ b1, const float* __restrict__ rn1,
    float* __restrict__ dists, unsigned char* __restrict__ m1q,
    unsigned short* __restrict__ h1hi, unsigned short* __restrict__ h1lo) {
    __shared__ __align__(16) unsigned short sm[8192];
    int m0 = blockIdx.x * 64, n0 = blockIdx.y * 64;
    f32x4 acc[2][2] = {};
    mfma3_64<D>(xhi, xlo, W1hi, W1lo, m0, n0, sm, acc);
    int l = threadIdx.x & 63, w = threadIdx.x >> 6;
    int quad = l >> 4, l16 = l & 15;
    int wm = (w >> 1) * 32, wn = (w & 1) * 32;
    #pragma unroll
    for (int mt = 0; mt < 2; mt++)
        #pragma unroll
        for (int nt = 0; nt < 2; nt++) {
            int n = n0 + wn + nt * 16 + l16;
            float bv = b1[n], rv = rn1[n];
            #pragma unroll
            for (int r = 0; r < 4; r++) {
                int m = m0 + wm + mt * 16 + quad * 4 + r;
                float z = acc[mt][nt][r] + bv;
                size_t idx = (size_t)m * D1 + n;
                dists[idx] = fabsf(z) / rv;
                m1q[idx] = (z > 0.f) ? 0xFFu : 0u;
                float h = z > 0.f ? z : 0.f;
                unsigned short hh = f2bf(h);
                h1hi[idx] = hh;
                h1lo[idx] = f2bf(h - bf2f(hh));
            }
        }
}

// ---- layer 2: also emits m2q bytes -----------------------------------------
__global__ __launch_bounds__(256) void k_l2(
    const unsigned short* __restrict__ h1hi, const unsigned short* __restrict__ h1lo,
    const unsigned short* __restrict__ W2hi, const unsigned short* __restrict__ W2lo,
    const float* __restrict__ b2, float* __restrict__ z2,
    unsigned char* __restrict__ m2q,
    unsigned short* __restrict__ h2hi, unsigned short* __restrict__ h2lo) {
    __shared__ __align__(16) unsigned short sm[8192];
    int m0 = blockIdx.x * 64, n0 = blockIdx.y * 64;
    f32x4 acc[2][2] = {};
    mfma3_64<D1>(h1hi, h1lo, W2hi, W2lo, m0, n0, sm, acc);
    int l = threadIdx.x & 63, w = threadIdx.x >> 6;
    int quad = l >> 4, l16 = l & 15;
    int wm = (w >> 1) * 32, wn = (w & 1) * 32;
    #pragma unroll
    for (int mt = 0; mt < 2; mt++)
        #pragma unroll
        for (int nt = 0; nt < 2; nt++) {
            int n = n0 + wn + nt * 16 + l16;
            float bv = b2[n];
            #pragma unroll
            for (int r = 0; r < 4; r++) {
                int m = m0 + wm + mt * 16 + quad * 4 + r;
                float z = acc[mt][nt][r] + bv;
                size_t idx = (size_t)m * D2 + n;
                z2[idx] = z;
                m2q[idx] = (z > 0.f) ? 0xFFu : 0u;
                float h = z > 0.f ? z : 0.f;
                unsigned short hh = f2bf(h);
                h2hi[idx] = hh;
                h2lo[idx] = f2bf(h - bf2f(hh));
            }
        }
}

// ---- layer 3 ---------------------------------------------------------------
__global__ __launch_bounds__(256) void k_l3(
    const unsigned short* __restrict__ h2hi, const unsigned short* __restrict__ h2lo,
    const unsigned short* __restrict__ W3hi, const unsigned short* __restrict__ W3lo,
    const float* __restrict__ b3, float* __restrict__ z3) {
    __shared__ __align__(16) unsigned short sm[8192];
    int m0 = blockIdx.x * 64, n0 = blockIdx.y * 64;
    f32x4 acc[2][2] = {};
    mfma3_64<D2>(h2hi, h2lo, W3hi, W3lo, m0, n0, sm, acc);
    int l = threadIdx.x & 63, w = threadIdx.x >> 6;
    int quad = l >> 4, l16 = l & 15;
    int wm = (w >> 1) * 32, wn = (w & 1) * 32;
    #pragma unroll
    for (int mt = 0; mt < 2; mt++)
        #pragma unroll
        for (int nt = 0; nt < 2; nt++) {
            int n = n0 + wn + nt * 16 + l16;
            float bv = b3[n];
            #pragma unroll
            for (int r = 0; r < 4; r++) {
                int m = m0 + wm + mt * 16 + quad * 4 + r;
                z3[(size_t)m * D3 + n] = acc[mt][nt][r] + bv;
            }
        }
}

// ---- GEMM1 (i8): C[o][d] = sum_i W2[o][i] * (m1 & W1T)[d][i] ---------------
// M=o(512), N=d(256), tile 128x128, BK=64, mask on B fragments.
// Epilogue: norm2[o] atomics + packed int8 qV2[d][o] dword stores.
__global__ __launch_bounds__(256) void k_gemm1(
    const signed char* __restrict__ W2i8,    // [512][1024]  A rows (o)
    const signed char* __restrict__ W1Ti8,   // [256][1024]  B rows (d)
    const unsigned char* __restrict__ m1q,   // [B][1024]
    const float* __restrict__ saq,           // [256]
    const float* __restrict__ sbq,           // [512]
    signed char* __restrict__ qV2,           // [CH][256][512] (d-major)
    float* __restrict__ norm2,               // [B][512]
    int b0) {
    __shared__ __align__(16) signed char As[8192];   // 128 rows x 64B
    __shared__ __align__(16) signed char Bs[8192];
    int m0 = blockIdx.x * 128;        // o
    int n0 = blockIdx.y * 128;        // d
    int bc = blockIdx.z;
    int b = b0 + bc;
    int tid = threadIdx.x;
    int l = tid & 63, w = tid >> 6;
    int rsub = l >> 2, cq = l & 3;
    int quad = l >> 4, l16 = l & 15;
    int wm = (w >> 1) * 64, wn = (w & 1) * 64;
    const unsigned char* mrow = m1q + (size_t)b * D1;

    const signed char* pa[2];
    const signed char* pb[2];
    #pragma unroll
    for (int r = 0; r < 2; r++) {
        int rloc = w * 32 + r * 16 + rsub;
        int c = (cq + ((rsub >> 1) & 3)) & 3;
        pa[r] = W2i8 + (size_t)(m0 + rloc) * D1 + c * 16;
        pb[r] = W1Ti8 + (size_t)(n0 + rloc) * D1 + c * 16;
    }
    int hq = (l16 >> 1) & 3;
    int slot = ((quad - hq) & 3) * 16;
    int aoff[4], boff[4];
    #pragma unroll
    for (int mt = 0; mt < 4; mt++) aoff[mt] = (wm + mt * 16 + l16) * 64 + slot;
    #pragma unroll
    for (int nt = 0; nt < 4; nt++) boff[nt] = (wn + nt * 16 + l16) * 64 + slot;

    i32x4 acc[4][4];
    #pragma unroll
    for (int i = 0; i < 4; i++)
        #pragma unroll
        for (int j = 0; j < 4; j++) acc[i][j] = (i32x4)0;

    for (int kk = 0; kk < D1; kk += 64) {
        #pragma unroll
        for (int r = 0; r < 2; r++) {
            gld16(pa[r] + kk, As + w * 2048 + r * 1024);
            gld16(pb[r] + kk, Bs + w * 2048 + r * 1024);
        }
        i32x4 mv = *(const i32x4*)(mrow + kk + quad * 16);
        __syncthreads();
        i32x4 a[4], bq[4];
        #pragma unroll
        for (int mt = 0; mt < 4; mt++)
            a[mt] = *(const i32x4*)(As + aoff[mt]);
        #pragma unroll
        for (int nt = 0; nt < 4; nt++)
            bq[nt] = (*(const i32x4*)(Bs + boff[nt])) & mv;
        #pragma unroll
        for (int mt = 0; mt < 4; mt++)
            #pragma unroll
            for (int nt = 0; nt < 4; nt++)
                acc[mt][nt] = __builtin_amdgcn_mfma_i32_16x16x64_i8(
                    a[mt], bq[nt], acc[mt][nt], 0, 0, 0);
        __syncthreads();
    }

    // scales: o per (mt,r) rows; d per (nt) cols
    float sbd[4][4];
    #pragma unroll
    for (int mt = 0; mt < 4; mt++)
        #pragma unroll
        for (int r = 0; r < 4; r++)
            sbd[mt][r] = sbq[m0 + wm + mt * 16 + quad * 4 + r] * (1.0f / CQ);
    float saCQ[4];
    #pragma unroll
    for (int nt = 0; nt < 4; nt++)
        saCQ[nt] = saq[n0 + wn + nt * 16 + l16] * CQ;

    // norm2[o] += sum_d V2^2 ; V2 = (acc*sb/CQ)*(sa*CQ)
    #pragma unroll
    for (int mt = 0; mt < 4; mt++)
        #pragma unroll
        for (int r = 0; r < 4; r++) {
            float s = 0.f;
            #pragma unroll
            for (int nt = 0; nt < 4; nt++) {
                float v = (float)acc[mt][nt][r] * sbd[mt][r] * saCQ[nt];
                s += v * v;
            }
            s += __shfl_down(s, 8, 64);
            s += __shfl_down(s, 4, 64);
            s += __shfl_down(s, 2, 64);
            s += __shfl_down(s, 1, 64);
            if (l16 == 0)
                atomicAdd(&norm2[(size_t)b * D2 + m0 + wm + mt * 16 + quad * 4 + r], s);
        }

    // qV2[d][o]: pack 4 consecutive-o int8 per dword
    signed char* qb = qV2 + (size_t)bc * (D * D2);
    #pragma unroll
    for (int nt = 0; nt < 4; nt++) {
        int d = n0 + wn + nt * 16 + l16;
        #pragma unroll
        for (int mt = 0; mt < 4; mt++) {
            int obase = m0 + wm + mt * 16 + quad * 4;
            unsigned int pk = 0;
            #pragma unroll
            for (int r = 0; r < 4; r++) {
                int qi = __float2int_rn((float)acc[mt][nt][r] * sbd[mt][r]);
                qi = max(-127, min(127, qi));
                pk |= ((unsigned int)(qi & 255)) << (8 * r);
            }
            *(unsigned int*)(qb + (size_t)d * D2 + obase) = pk;
        }
    }
}

// ---- GEMM2 (i8): norm3[b][p] += s3[p]^2 * sum_d (saCQ[d]*S3[p][d])^2 -------
// S3[p][d] = sum_o qW3[p][o] * (m2 & qV2)[d][o].  M=p(256),N=d(256),K=o(512).
__global__ __launch_bounds__(256) void k_gemm2(
    const signed char* __restrict__ W3i8,    // [256][512]
    const signed char* __restrict__ qV2,     // [CH][256][512]
    const unsigned char* __restrict__ m2q,   // [B][512]
    const float* __restrict__ saq,           // [256]
    const float* __restrict__ s3q,           // [256]
    float* __restrict__ norm3,               // [B][256]
    int b0) {
    __shared__ __align__(16) signed char As[8192];
    __shared__ __align__(16) signed char Bs[8192];
    int m0 = blockIdx.x * 128;        // p
    int n0 = blockIdx.y * 128;        // d
    int bc = blockIdx.z;
    int b = b0 + bc;
    int tid = threadIdx.x;
    int l = tid & 63, w = tid >> 6;
    int rsub = l >> 2, cq = l & 3;
    int quad = l >> 4, l16 = l & 15;
    int wm = (w >> 1) * 64, wn = (w & 1) * 64;
    const unsigned char* mrow = m2q + (size_t)b * D2;
    const signed char* Bsrc = qV2 + (size_t)bc * (D * D2);

    const signed char* pa[2];
    const signed char* pb[2];
    #pragma unroll
    for (int r = 0; r < 2; r++) {
        int rloc = w * 32 + r * 16 + rsub;
        int c = (cq + ((rsub >> 1) & 3)) & 3;
        pa[r] = W3i8 + (size_t)(m0 + rloc) * D2 + c * 16;
        pb[r] = Bsrc + (size_t)(n0 + rloc) * D2 + c * 16;
    }
    int hq = (l16 >> 1) & 3;
    int slot = ((quad - hq) & 3) * 16;
    int aoff[4], boff[4];
    #pragma unroll
    for (int mt = 0; mt < 4; mt++) aoff[mt] = (wm + mt * 16 + l16) * 64 + slot;
    #pragma unroll
    for (int nt = 0; nt < 4; nt++) boff[nt] = (wn + nt * 16 + l16) * 64 + slot;

    i32x4 acc[4][4];
    #pragma unroll
    for (int i = 0; i < 4; i++)
        #pragma unroll
        for (int j = 0; j < 4; j++) acc[i][j] = (i32x4)0;

    for (int kk = 0; kk < D2; kk += 64) {
        #pragma unroll
        for (int r = 0; r < 2; r++) {
            gld16(pa[r] + kk, As + w * 2048 + r * 1024);
            gld16(pb[r] + kk, Bs + w * 2048 + r * 1024);
        }
        i32x4 mv = *(const i32x4*)(mrow + kk + quad * 16);
        __syncthreads();
        i32x4 a[4], bq[4];
        #pragma unroll
        for (int mt = 0; mt < 4; mt++)
            a[mt] = *(const i32x4*)(As + aoff[mt]);
        #pragma unroll
        for (int nt = 0; nt < 4; nt++)
            bq[nt] = (*(const i32x4*)(Bs + boff[nt])) & mv;
        #pragma unroll
        for (int mt = 0; mt < 4; mt++)
            #pragma unroll
            for (int nt = 0; nt < 4; nt++)
                acc[mt][nt] = __builtin_amdgcn_mfma_i32_16x16x64_i8(
                    a[mt], bq[nt], acc[mt][nt], 0, 0, 0);
        __syncthreads();
    }

    float saCQ[4];
    #pragma unroll
    for (int nt = 0; nt < 4; nt++)
        saCQ[nt] = saq[n0 + wn + nt * 16 + l16] * CQ;

    #pragma unroll
    for (int mt = 0; mt < 4; mt++)
        #pragma unroll
        for (int r = 0; r < 4; r++) {
            float s = 0.f;
            #pragma unroll
            for (int nt = 0; nt < 4; nt++) {
                float v = (float)acc[mt][nt][r] * saCQ[nt];
                s += v * v;
            }
            s += __shfl_down(s, 8, 64);
            s += __shfl_down(s, 4, 64);
            s += __shfl_down(s, 2, 64);
            s += __shfl_down(s, 1, 64);
            if (l16 == 0) {
                int p = m0 + wm + mt * 16 + quad * 4 + r;
                float s3 = s3q[p];
                atomicAdd(&norm3[(size_t)b * D3 + p], s * s3 * s3);
            }
        }
}

// ---- per-batch k-smallest sum; dist2/dist3 inline; atomic to out -----------
__global__ __launch_bounds__(256) void k_topk(
    const float* __restrict__ dists,    // [B][D1] dist1 only
    const float* __restrict__ z2, const float* __restrict__ norm2,
    const float* __restrict__ z3, const float* __restrict__ norm3,
    const int* __restrict__ kp, float* __restrict__ outp) {
    __shared__ unsigned long long wmin[4];
    int b = blockIdx.x, t = threadIdx.x;
    float lv[7];
    #pragma unroll
    for (int j = 0; j < 4; j++) lv[j] = dists[(size_t)b * D1 + t + 256 * j];
    #pragma unroll
    for (int j = 4; j < 6; j++) {
        int o = t + 256 * j - 1024;
        lv[j] = fabsf(z2[(size_t)b * D2 + o]) / sqrtf(norm2[(size_t)b * D2 + o]);
    }
    lv[6] = fabsf(z3[(size_t)b * D3 + t]) / sqrtf(norm3[(size_t)b * D3 + t]);
    int k = *kp;
    if (k > NDIST) k = NDIST;
    float sum = 0.f;
    for (int it = 0; it < k; it++) {
        float mv = lv[0]; int mj = 0;
        #pragma unroll
        for (int j = 1; j < 7; j++)
            if (lv[j] < mv) { mv = lv[j]; mj = j; }
        unsigned long long key =
            ((unsigned long long)__float_as_uint(mv) << 32) | (unsigned)(t * 8 + mj);
        #pragma unroll
        for (int off = 32; off > 0; off >>= 1) {
            unsigned long long o = __shfl_down(key, off, 64);
            if (o < key) key = o;
        }
        if ((t & 63) == 0) wmin[t >> 6] = key;
        __syncthreads();
        unsigned long long k0 = wmin[0];
        #pragma unroll
        for (int ww = 1; ww < 4; ww++) if (wmin[ww] < k0) k0 = wmin[ww];
        sum += __uint_as_float((unsigned)(k0 >> 32));
        int wt = (int)((k0 & 0xFFFu) >> 3), wj = (int)(k0 & 7u);
        if (t == wt) lv[wj] = FLT_MAX;
        __syncthreads();
    }
    if (t == 0) atomicAdd(outp, sum);
}

extern "C" void kernel_launch(void* const* d_in, const int* in_sizes, int n_in,
                              void* d_out, int out_size, void* d_ws, size_t ws_size,
                              hipStream_t stream) {
    const float* x  = (const float*)d_in[0];
    const float* W1 = (const float*)d_in[1];
    const float* b1 = (const float*)d_in[2];
    const float* W2 = (const float*)d_in[3];
    const float* b2 = (const float*)d_in[4];
    const float* W3 = (const float*)d_in[5];
    const float* b3 = (const float*)d_in[6];
    const int*   kp = (const int*)d_in[7];
    float* outp = (float*)d_out;

    float* fp = (float*)d_ws;
    float* rn1     = fp;                          fp += D1;
    float* z2      = fp;                          fp += (size_t)B * D2;
    float* z3      = fp;                          fp += (size_t)B * D3;
    float* dists   = fp;                          fp += (size_t)B * D1;
    float* norm2   = fp;                          fp += (size_t)B * D2;   // norm2,norm3 contiguous
    float* norm3   = fp;                          fp += (size_t)B * D3;
    float* saq     = fp;                          fp += D;
    float* sbq     = fp;                          fp += D2;
    float* s3q     = fp;                          fp += D3;
    unsigned short* up = (unsigned short*)fp;
    unsigned short* W2hi  = up;  up += (size_t)D2 * D1;
    unsigned short* W2lo  = up;  up += (size_t)D2 * D1;
    unsigned short* W3hi  = up;  up += (size_t)D3 * D2;
    unsigned short* W3lo  = up;  up += (size_t)D3 * D2;
    unsigned short* xhi   = up;  up += (size_t)B * D;
    unsigned short* xlo   = up;  up += (size_t)B * D;
    unsigned short* W1hi  = up;  up += (size_t)D1 * D;
    unsigned short* W1lo  = up;  up += (size_t)D1 * D;
    unsigned short* h1hi  = up;  up += (size_t)B * D1;
    unsigned short* h1lo  = up;  up += (size_t)B * D1;
    unsigned short* h2hi  = up;  up += (size_t)B * D2;
    unsigned short* h2lo  = up;  up += (size_t)B * D2;
    signed char*    cp = (signed char*)up;
    signed char*    W1Ti8 = cp;  cp += (size_t)D * D1;
    signed char*    W2i8  = cp;  cp += (size_t)D2 * D1;
    signed char*    W3i8  = cp;  cp += (size_t)D3 * D2;
    unsigned char*  m1q   = (unsigned char*)cp;  cp += (size_t)B * D1;
    unsigned char*  m2q   = (unsigned char*)cp;  cp += (size_t)B * D2;
    signed char*    qV2   = cp;

    size_t base_bytes = (size_t)((char*)qV2 - (char*)d_ws);
    int CH = 8;
    const int cands[6] = {256, 128, 64, 32, 16, 8};
    for (int c = 0; c < 6; c++) {
        size_t need = base_bytes + (size_t)cands[c] * D * D2;
        if (need <= ws_size) { CH = cands[c]; break; }
    }

    k_prep<<<2208, 256, 0, stream>>>(x, W1, W2, W3, norm2, outp,
                                     xhi, xlo, W1hi, W1lo, W2hi, W2lo, W3hi, W3lo,
                                     W1Ti8, saq, W2i8, sbq, W3i8, s3q, rn1);

    k_l1<<<dim3(B / 64, D1 / 64), 256, 0, stream>>>(xhi, xlo, W1hi, W1lo, b1, rn1,
                                                    dists, m1q, h1hi, h1lo);
    k_l2<<<dim3(B / 64, D2 / 64), 256, 0, stream>>>(h1hi, h1lo, W2hi, W2lo, b2,
                                                    z2, m2q, h2hi, h2lo);
    k_l3<<<dim3(B / 64, D3 / 64), 256, 0, stream>>>(h2hi, h2lo, W3hi, W3lo, b3, z3);

    for (int b0 = 0; b0 < B; b0 += CH) {
        k_gemm1<<<dim3(D2 / 128, D / 128, CH), 256, 0, stream>>>(
            W2i8, W1Ti8, m1q, saq, sbq, qV2, norm2, b0);
        k_gemm2<<<dim3(D3 / 128, D / 128, CH), 256, 0, stream>>>(
            W3i8, qV2, m2q, saq, s3q, norm3, b0);
    }

    k_topk<<<B, 256, 0, stream>>>(dists, z2, norm2, z3, norm3, kp, outp);
}